// Round 1
// baseline (3151.819 us; speedup 1.0000x reference)
//
#include <hip/hip_runtime.h>

#define NN 50000
#define NE 800000
#define NF 128

// ---------------------------------------------------------------------------
// K1: per-edge degree counts: cnt[row] += 1 (num_neighbor), degc[col] += 1
// ---------------------------------------------------------------------------
__global__ void count_kernel(const int* __restrict__ ei, float* __restrict__ cnt,
                             float* __restrict__ degc) {
    int e = blockIdx.x * blockDim.x + threadIdx.x;
    if (e >= NE) return;
    int r = ei[e];
    int c = ei[NE + e];
    atomicAdd(&cnt[r], 1.0f);
    atomicAdd(&degc[c], 1.0f);
}

// ---------------------------------------------------------------------------
// K2: neigh_sum[row] += x[col]   (thread per edge x float4 chunk)
// ---------------------------------------------------------------------------
__global__ void scatter_x_kernel(const int* __restrict__ ei, const float* __restrict__ x,
                                 float* __restrict__ nsum) {
    int idx = blockIdx.x * blockDim.x + threadIdx.x;
    if (idx >= NE * 32) return;
    int e = idx >> 5, q = idx & 31;
    int r = ei[e], c = ei[NE + e];
    float4 v = ((const float4*)x)[c * 32 + q];
    float* dst = nsum + r * NF + q * 4;
    atomicAdd(dst + 0, v.x);
    atomicAdd(dst + 1, v.y);
    atomicAdd(dst + 2, v.z);
    atomicAdd(dst + 3, v.w);
}

// ---------------------------------------------------------------------------
// K3a: neighbor = neigh_sum / max(cnt,1)   (in place)
// ---------------------------------------------------------------------------
__global__ void neigh_norm_kernel(float* __restrict__ nsum, const float* __restrict__ cnt) {
    int idx = blockIdx.x * blockDim.x + threadIdx.x;
    if (idx >= NN * NF) return;
    int i = idx >> 7;
    nsum[idx] = nsum[idx] / fmaxf(cnt[i], 1.0f);
}

// ---------------------------------------------------------------------------
// K3b: dinv = rsqrt(col_degree + 1)  (self loop included, always > 0)
// ---------------------------------------------------------------------------
__global__ void dinv_kernel(const float* __restrict__ degc, float* __restrict__ dinv) {
    int i = blockIdx.x * blockDim.x + threadIdx.x;
    if (i >= NN) return;
    dinv[i] = rsqrtf(degc[i] + 1.0f);
}

// ---------------------------------------------------------------------------
// K4: fused FiLM + xw GEMM. 16 nodes per block, 128 threads (thread = out feat).
// Computes: gamma = lrelu(x@g1^T + nb@g2^T)+1 ; beta = lrelu(x@b1^T + nb@b2^T)
//           output = x + gamma*r + beta - nb     -> d_out second half
//           xw = x @ lin^T                       -> workspace
// ---------------------------------------------------------------------------
__global__ __launch_bounds__(128) void film_kernel(
    const float* __restrict__ x, const float* __restrict__ nb,
    const float* __restrict__ g1, const float* __restrict__ g2,
    const float* __restrict__ b1, const float* __restrict__ b2,
    const float* __restrict__ rvec, const float* __restrict__ lin,
    float* __restrict__ xw, float* __restrict__ outp) {
    __shared__ __align__(16) float xs[16][NF];
    __shared__ __align__(16) float ns[16][NF];
    int t = threadIdx.x;
    int node0 = blockIdx.x * 16;
    #pragma unroll
    for (int i = 0; i < 16; ++i) {
        int n = node0 + i;
        xs[i][t] = x[n * NF + t];
        ns[i][t] = nb[n * NF + t];
    }
    __syncthreads();

    const float* w0 = g1 + t * NF;
    const float* w1 = g2 + t * NF;
    const float* w2 = b1 + t * NF;
    const float* w3 = b2 + t * NF;
    const float* w4 = lin + t * NF;
    float a0[16] = {0}, a1[16] = {0}, a2[16] = {0}, a3[16] = {0}, a4[16] = {0};

    for (int k = 0; k < NF; k += 4) {
        float4 W0 = *(const float4*)(w0 + k);
        float4 W1 = *(const float4*)(w1 + k);
        float4 W2 = *(const float4*)(w2 + k);
        float4 W3 = *(const float4*)(w3 + k);
        float4 W4 = *(const float4*)(w4 + k);
        #pragma unroll
        for (int i = 0; i < 16; ++i) {
            float4 xv = *(const float4*)(&xs[i][k]);
            float4 nv = *(const float4*)(&ns[i][k]);
            a0[i] += xv.x * W0.x + xv.y * W0.y + xv.z * W0.z + xv.w * W0.w;
            a1[i] += nv.x * W1.x + nv.y * W1.y + nv.z * W1.z + nv.w * W1.w;
            a2[i] += xv.x * W2.x + xv.y * W2.y + xv.z * W2.z + xv.w * W2.w;
            a3[i] += nv.x * W3.x + nv.y * W3.y + nv.z * W3.z + nv.w * W3.w;
            a4[i] += xv.x * W4.x + xv.y * W4.y + xv.z * W4.z + xv.w * W4.w;
        }
    }

    float rf = rvec[t];
    #pragma unroll
    for (int i = 0; i < 16; ++i) {
        int n = node0 + i;
        float gp = a0[i] + a1[i];
        float bp = a2[i] + a3[i];
        float gamma = (gp >= 0.f ? gp : 0.2f * gp) + 1.0f;
        float beta  = (bp >= 0.f ? bp : 0.2f * bp);
        float o = xs[i][t] + gamma * rf + beta - ns[i][t];
        outp[n * NF + t] = o;
        xw[n * NF + t]   = a4[i];
    }
}

// ---------------------------------------------------------------------------
// K5: GCN edge scatter: hk[col] += dinv[row]*dinv[col] * xw[row]
// ---------------------------------------------------------------------------
__global__ void gcn_scatter_kernel(const int* __restrict__ ei, const float* __restrict__ xw,
                                   const float* __restrict__ dinv, float* __restrict__ hk) {
    int idx = blockIdx.x * blockDim.x + threadIdx.x;
    if (idx >= NE * 32) return;
    int e = idx >> 5, q = idx & 31;
    int r = ei[e], c = ei[NE + e];
    float nrm = dinv[r] * dinv[c];
    float4 v = ((const float4*)xw)[r * 32 + q];
    float* dst = hk + c * NF + q * 4;
    atomicAdd(dst + 0, nrm * v.x);
    atomicAdd(dst + 1, nrm * v.y);
    atomicAdd(dst + 2, nrm * v.z);
    atomicAdd(dst + 3, nrm * v.w);
}

// ---------------------------------------------------------------------------
// K6: h_s = output @ lin^T ; h_k = (hk + dinv^2*xw + bias + h_s) / (cnt + 1)
// ---------------------------------------------------------------------------
__global__ __launch_bounds__(128) void final_kernel(
    const float* __restrict__ outp, const float* __restrict__ lin,
    const float* __restrict__ hk, const float* __restrict__ xw,
    const float* __restrict__ dinv, const float* __restrict__ cnt,
    const float* __restrict__ bias, float* __restrict__ hko) {
    __shared__ __align__(16) float os[16][NF];
    int t = threadIdx.x;
    int node0 = blockIdx.x * 16;
    #pragma unroll
    for (int i = 0; i < 16; ++i) os[i][t] = outp[(node0 + i) * NF + t];
    __syncthreads();

    const float* w = lin + t * NF;
    float acc[16] = {0};
    for (int k = 0; k < NF; k += 4) {
        float4 W = *(const float4*)(w + k);
        #pragma unroll
        for (int i = 0; i < 16; ++i) {
            float4 ov = *(const float4*)(&os[i][k]);
            acc[i] += ov.x * W.x + ov.y * W.y + ov.z * W.z + ov.w * W.w;
        }
    }

    float bf = bias[t];
    #pragma unroll
    for (int i = 0; i < 16; ++i) {
        int n = node0 + i;
        float di = dinv[n];
        float hv = hk[n * NF + t] + di * di * xw[n * NF + t] + bf + acc[i];
        hko[n * NF + t] = hv / (cnt[n] + 1.0f);
    }
}

// ---------------------------------------------------------------------------
extern "C" void kernel_launch(void* const* d_in, const int* in_sizes, int n_in,
                              void* d_out, int out_size, void* d_ws, size_t ws_size,
                              hipStream_t stream) {
    const float* x    = (const float*)d_in[0];
    const int*   ei   = (const int*)d_in[1];
    const float* g1   = (const float*)d_in[3];
    const float* g2   = (const float*)d_in[4];
    const float* b1   = (const float*)d_in[5];
    const float* b2   = (const float*)d_in[6];
    const float* rv   = (const float*)d_in[7];
    const float* lin  = (const float*)d_in[8];
    const float* bias = (const float*)d_in[9];

    float* ws   = (float*)d_ws;
    float* nsum = ws;                 // N*F  (becomes neighbor in place)
    float* hk   = nsum + NN * NF;     // N*F
    float* cnt  = hk + NN * NF;       // N
    float* degc = cnt + NN;           // N
    float* xw   = degc + NN;          // N*F
    float* dinv = xw + NN * NF;       // N

    float* hko  = (float*)d_out;      // N*F  (h_k)
    float* outp = hko + NN * NF;      // N*F  (output)

    // zero the accumulated buffers: nsum, hk, cnt, degc (contiguous)
    size_t zero_bytes = (size_t)(2 * NN * NF + 2 * NN) * sizeof(float);
    hipMemsetAsync(d_ws, 0, zero_bytes, stream);

    count_kernel<<<(NE + 255) / 256, 256, 0, stream>>>(ei, cnt, degc);
    scatter_x_kernel<<<(NE * 32 + 255) / 256, 256, 0, stream>>>(ei, x, nsum);
    neigh_norm_kernel<<<(NN * NF + 255) / 256, 256, 0, stream>>>(nsum, cnt);
    dinv_kernel<<<(NN + 255) / 256, 256, 0, stream>>>(degc, dinv);
    film_kernel<<<NN / 16, 128, 0, stream>>>(x, nsum, g1, g2, b1, b2, rv, lin, xw, outp);
    gcn_scatter_kernel<<<(NE * 32 + 255) / 256, 256, 0, stream>>>(ei, xw, dinv, hk);
    final_kernel<<<NN / 16, 128, 0, stream>>>(outp, lin, hk, xw, dinv, cnt, bias, hko);
}

// Round 2
// 757.419 us; speedup vs baseline: 4.1613x; 4.1613x over previous
//
#include <hip/hip_runtime.h>

#define NN 50000
#define NE 800000
#define NF 128

// ---------------------------------------------------------------------------
// K1: integer degree counts. deg_r[row]++ (num_neighbor), deg_c[col]++ (GCN deg)
// ---------------------------------------------------------------------------
__global__ void degree_kernel(const int* __restrict__ ei, int* __restrict__ deg_r,
                              int* __restrict__ deg_c) {
    int e = blockIdx.x * blockDim.x + threadIdx.x;
    if (e >= NE) return;
    atomicAdd(&deg_r[ei[e]], 1);
    atomicAdd(&deg_c[ei[NE + e]], 1);
}

// ---------------------------------------------------------------------------
// K2: dinv = rsqrt(col_degree + 1)  (self loop included, always > 0)
// ---------------------------------------------------------------------------
__global__ void dinv_kernel(const int* __restrict__ deg_c, float* __restrict__ dinv) {
    int i = blockIdx.x * blockDim.x + threadIdx.x;
    if (i >= NN) return;
    dinv[i] = rsqrtf((float)deg_c[i] + 1.0f);
}

// ---------------------------------------------------------------------------
// K3: exclusive prefix scan of both degree arrays (one block each, grid=2).
// Writes offs[0..NN] and initializes cursor copy for the bucket scatter.
// ---------------------------------------------------------------------------
#define SCAN_T 1024
#define SCAN_CHUNK 49   // 1024*49 >= 50000
__global__ __launch_bounds__(SCAN_T) void scan_kernel(
    const int* __restrict__ deg_r, const int* __restrict__ deg_c,
    int* __restrict__ offs_r, int* __restrict__ offs_c,
    int* __restrict__ cur_r, int* __restrict__ cur_c) {
    const int* deg = blockIdx.x ? deg_c : deg_r;
    int* offs = blockIdx.x ? offs_c : offs_r;
    int* cur  = blockIdx.x ? cur_c  : cur_r;

    __shared__ int part[SCAN_T];
    int t = threadIdx.x;
    int lo = t * SCAN_CHUNK;
    int hi = min(lo + SCAN_CHUNK, NN);
    int s = 0;
    for (int i = lo; i < hi; ++i) s += deg[i];
    part[t] = s;
    __syncthreads();
    for (int off = 1; off < SCAN_T; off <<= 1) {
        int v = (t >= off) ? part[t - off] : 0;
        __syncthreads();
        part[t] += v;
        __syncthreads();
    }
    int run = (t > 0) ? part[t - 1] : 0;   // exclusive base
    for (int i = lo; i < hi; ++i) {
        offs[i] = run;
        cur[i]  = run;
        run += deg[i];
    }
    if (t == SCAN_T - 1) offs[NN] = run;   // == NE
}

// ---------------------------------------------------------------------------
// K4: bucket edges. csr_r[row-bucket] = col ; csr_c[col-bucket] = row
// ---------------------------------------------------------------------------
__global__ void bucket_kernel(const int* __restrict__ ei, int* __restrict__ cur_r,
                              int* __restrict__ cur_c, int* __restrict__ csr_r,
                              int* __restrict__ csr_c) {
    int e = blockIdx.x * blockDim.x + threadIdx.x;
    if (e >= NE) return;
    int r = ei[e];
    int c = ei[NE + e];
    int p = atomicAdd(&cur_r[r], 1);
    csr_r[p] = c;
    int q = atomicAdd(&cur_c[c], 1);
    csr_c[q] = r;
}

// ---------------------------------------------------------------------------
// K5: neighbor[n] = mean over csr_r[n] of x[src].  32 lanes per node (float4),
// 8 nodes per 256-thread block.
// ---------------------------------------------------------------------------
__global__ __launch_bounds__(256) void gather_x_kernel(
    const int* __restrict__ offs_r, const int* __restrict__ csr_r,
    const float* __restrict__ x, float* __restrict__ neighbor) {
    int g = blockIdx.x * 8 + (threadIdx.x >> 5);
    int l = threadIdx.x & 31;
    if (g >= NN) return;
    int s = offs_r[g], e2 = offs_r[g + 1];
    float4 acc = {0.f, 0.f, 0.f, 0.f};
    for (int j = s; j < e2; ++j) {
        int src = csr_r[j];
        float4 v = ((const float4*)x)[src * 32 + l];
        acc.x += v.x; acc.y += v.y; acc.z += v.z; acc.w += v.w;
    }
    float inv = 1.0f / fmaxf((float)(e2 - s), 1.0f);
    acc.x *= inv; acc.y *= inv; acc.z *= inv; acc.w *= inv;
    ((float4*)neighbor)[g * 32 + l] = acc;
}

// ---------------------------------------------------------------------------
// K6: fused FiLM + xw GEMM. 16 nodes per block, 128 threads (thread = out feat).
// ---------------------------------------------------------------------------
__global__ __launch_bounds__(128) void film_kernel(
    const float* __restrict__ x, const float* __restrict__ nb,
    const float* __restrict__ g1, const float* __restrict__ g2,
    const float* __restrict__ b1, const float* __restrict__ b2,
    const float* __restrict__ rvec, const float* __restrict__ lin,
    float* __restrict__ xw, float* __restrict__ outp) {
    __shared__ __align__(16) float xs[16][NF];
    __shared__ __align__(16) float ns[16][NF];
    int t = threadIdx.x;
    int node0 = blockIdx.x * 16;
    #pragma unroll
    for (int i = 0; i < 16; ++i) {
        int n = node0 + i;
        xs[i][t] = x[n * NF + t];
        ns[i][t] = nb[n * NF + t];
    }
    __syncthreads();

    const float* w0 = g1 + t * NF;
    const float* w1 = g2 + t * NF;
    const float* w2 = b1 + t * NF;
    const float* w3 = b2 + t * NF;
    const float* w4 = lin + t * NF;
    float a0[16] = {0}, a1[16] = {0}, a2[16] = {0}, a3[16] = {0}, a4[16] = {0};

    for (int k = 0; k < NF; k += 4) {
        float4 W0 = *(const float4*)(w0 + k);
        float4 W1 = *(const float4*)(w1 + k);
        float4 W2 = *(const float4*)(w2 + k);
        float4 W3 = *(const float4*)(w3 + k);
        float4 W4 = *(const float4*)(w4 + k);
        #pragma unroll
        for (int i = 0; i < 16; ++i) {
            float4 xv = *(const float4*)(&xs[i][k]);
            float4 nv = *(const float4*)(&ns[i][k]);
            a0[i] += xv.x * W0.x + xv.y * W0.y + xv.z * W0.z + xv.w * W0.w;
            a1[i] += nv.x * W1.x + nv.y * W1.y + nv.z * W1.z + nv.w * W1.w;
            a2[i] += xv.x * W2.x + xv.y * W2.y + xv.z * W2.z + xv.w * W2.w;
            a3[i] += nv.x * W3.x + nv.y * W3.y + nv.z * W3.z + nv.w * W3.w;
            a4[i] += xv.x * W4.x + xv.y * W4.y + xv.z * W4.z + xv.w * W4.w;
        }
    }

    float rf = rvec[t];
    #pragma unroll
    for (int i = 0; i < 16; ++i) {
        int n = node0 + i;
        float gp = a0[i] + a1[i];
        float bp = a2[i] + a3[i];
        float gamma = (gp >= 0.f ? gp : 0.2f * gp) + 1.0f;
        float beta  = (bp >= 0.f ? bp : 0.2f * bp);
        float o = xs[i][t] + gamma * rf + beta - ns[i][t];
        outp[n * NF + t] = o;
        xw[n * NF + t]   = a4[i];
    }
}

// ---------------------------------------------------------------------------
// K7: GCN aggregation as gather over csr_c, self-loop term folded in:
// hk[c] = dinv[c] * sum_{r in in(c)} dinv[r]*xw[r]  +  dinv[c]^2 * xw[c]
// ---------------------------------------------------------------------------
__global__ __launch_bounds__(256) void gather_gcn_kernel(
    const int* __restrict__ offs_c, const int* __restrict__ csr_c,
    const float* __restrict__ xw, const float* __restrict__ dinv,
    float* __restrict__ hk) {
    int g = blockIdx.x * 8 + (threadIdx.x >> 5);
    int l = threadIdx.x & 31;
    if (g >= NN) return;
    int s = offs_c[g], e2 = offs_c[g + 1];
    float4 acc = {0.f, 0.f, 0.f, 0.f};
    for (int j = s; j < e2; ++j) {
        int src = csr_c[j];
        float w = dinv[src];
        float4 v = ((const float4*)xw)[src * 32 + l];
        acc.x += w * v.x; acc.y += w * v.y; acc.z += w * v.z; acc.w += w * v.w;
    }
    float dc = dinv[g];
    float4 self = ((const float4*)xw)[g * 32 + l];
    acc.x = dc * acc.x + dc * dc * self.x;
    acc.y = dc * acc.y + dc * dc * self.y;
    acc.z = dc * acc.z + dc * dc * self.z;
    acc.w = dc * acc.w + dc * dc * self.w;
    ((float4*)hk)[g * 32 + l] = acc;
}

// ---------------------------------------------------------------------------
// K8: h_s = output @ lin^T ; h_k = (hk + bias + h_s) / (num_neighbor + 1)
// ---------------------------------------------------------------------------
__global__ __launch_bounds__(128) void final_kernel(
    const float* __restrict__ outp, const float* __restrict__ lin,
    const float* __restrict__ hk, const int* __restrict__ deg_r,
    const float* __restrict__ bias, float* __restrict__ hko) {
    __shared__ __align__(16) float os[16][NF];
    int t = threadIdx.x;
    int node0 = blockIdx.x * 16;
    #pragma unroll
    for (int i = 0; i < 16; ++i) os[i][t] = outp[(node0 + i) * NF + t];
    __syncthreads();

    const float* w = lin + t * NF;
    float acc[16] = {0};
    for (int k = 0; k < NF; k += 4) {
        float4 W = *(const float4*)(w + k);
        #pragma unroll
        for (int i = 0; i < 16; ++i) {
            float4 ov = *(const float4*)(&os[i][k]);
            acc[i] += ov.x * W.x + ov.y * W.y + ov.z * W.z + ov.w * W.w;
        }
    }

    float bf = bias[t];
    #pragma unroll
    for (int i = 0; i < 16; ++i) {
        int n = node0 + i;
        float hv = hk[n * NF + t] + bf + acc[i];
        hko[n * NF + t] = hv / ((float)deg_r[n] + 1.0f);
    }
}

// ---------------------------------------------------------------------------
extern "C" void kernel_launch(void* const* d_in, const int* in_sizes, int n_in,
                              void* d_out, int out_size, void* d_ws, size_t ws_size,
                              hipStream_t stream) {
    const float* x    = (const float*)d_in[0];
    const int*   ei   = (const int*)d_in[1];
    const float* g1   = (const float*)d_in[3];
    const float* g2   = (const float*)d_in[4];
    const float* b1   = (const float*)d_in[5];
    const float* b2   = (const float*)d_in[6];
    const float* rv   = (const float*)d_in[7];
    const float* lin  = (const float*)d_in[8];
    const float* bias = (const float*)d_in[9];

    float* ws      = (float*)d_ws;
    float* neighbor = ws;                        // N*F
    float* hk       = neighbor + NN * NF;        // N*F
    float* xw       = hk + NN * NF;              // N*F
    float* dinv     = xw + NN * NF;              // N
    int*   ibase    = (int*)(dinv + NN);
    int*   deg_r    = ibase;                     // N   (zeroed)
    int*   deg_c    = deg_r + NN;                // N   (zeroed)
    int*   offs_r   = deg_c + NN;                // N+1
    int*   offs_c   = offs_r + (NN + 1);         // N+1
    int*   cur_r    = offs_c + (NN + 1);         // N
    int*   cur_c    = cur_r + NN;                // N
    int*   csr_r    = cur_c + NN;                // E
    int*   csr_c    = csr_r + NE;                // E

    float* hko  = (float*)d_out;                 // N*F  (h_k)
    float* outp = hko + NN * NF;                 // N*F  (output)

    // zero only the degree counters
    hipMemsetAsync(deg_r, 0, 2 * NN * sizeof(int), stream);

    degree_kernel<<<(NE + 255) / 256, 256, 0, stream>>>(ei, deg_r, deg_c);
    dinv_kernel<<<(NN + 255) / 256, 256, 0, stream>>>(deg_c, dinv);
    scan_kernel<<<2, SCAN_T, 0, stream>>>(deg_r, deg_c, offs_r, offs_c, cur_r, cur_c);
    bucket_kernel<<<(NE + 255) / 256, 256, 0, stream>>>(ei, cur_r, cur_c, csr_r, csr_c);
    gather_x_kernel<<<NN / 8, 256, 0, stream>>>(offs_r, csr_r, x, neighbor);
    film_kernel<<<NN / 16, 128, 0, stream>>>(x, neighbor, g1, g2, b1, b2, rv, lin, xw, outp);
    gather_gcn_kernel<<<NN / 8, 256, 0, stream>>>(offs_c, csr_c, xw, dinv, hk);
    final_kernel<<<NN / 16, 128, 0, stream>>>(outp, lin, hk, deg_r, bias, hko);
}

// Round 3
// 507.617 us; speedup vs baseline: 6.2090x; 1.4921x over previous
//
#include <hip/hip_runtime.h>

#define NN 50000
#define NE 800000
#define NF 128

typedef __attribute__((ext_vector_type(4))) float f32x4;
typedef __attribute__((ext_vector_type(8))) short bf16x8;

__device__ __forceinline__ short f2bf(float f) {
    unsigned u = __float_as_uint(f);
    u += 0x7FFF + ((u >> 16) & 1);      // round-to-nearest-even
    return (short)(u >> 16);
}
__device__ __forceinline__ float bf2f(short s) {
    return __uint_as_float(((unsigned)(unsigned short)s) << 16);
}

// ---------------------------------------------------------------------------
// K1: integer degree counts. deg_r[row]++ (num_neighbor), deg_c[col]++ (GCN deg)
// ---------------------------------------------------------------------------
__global__ void degree_kernel(const int* __restrict__ ei, int* __restrict__ deg_r,
                              int* __restrict__ deg_c) {
    int e = blockIdx.x * blockDim.x + threadIdx.x;
    if (e >= NE) return;
    atomicAdd(&deg_r[ei[e]], 1);
    atomicAdd(&deg_c[ei[NE + e]], 1);
}

// ---------------------------------------------------------------------------
// K2: dinv = rsqrt(col_degree + 1)
// ---------------------------------------------------------------------------
__global__ void dinv_kernel(const int* __restrict__ deg_c, float* __restrict__ dinv) {
    int i = blockIdx.x * blockDim.x + threadIdx.x;
    if (i >= NN) return;
    dinv[i] = rsqrtf((float)deg_c[i] + 1.0f);
}

// ---------------------------------------------------------------------------
// K3: exclusive prefix scan of both degree arrays (one block each, grid=2).
// ---------------------------------------------------------------------------
#define SCAN_T 1024
#define SCAN_CHUNK 49
__global__ __launch_bounds__(SCAN_T) void scan_kernel(
    const int* __restrict__ deg_r, const int* __restrict__ deg_c,
    int* __restrict__ offs_r, int* __restrict__ offs_c,
    int* __restrict__ cur_r, int* __restrict__ cur_c) {
    const int* deg = blockIdx.x ? deg_c : deg_r;
    int* offs = blockIdx.x ? offs_c : offs_r;
    int* cur  = blockIdx.x ? cur_c  : cur_r;

    __shared__ int part[SCAN_T];
    int t = threadIdx.x;
    int lo = t * SCAN_CHUNK;
    int hi = min(lo + SCAN_CHUNK, NN);
    int s = 0;
    for (int i = lo; i < hi; ++i) s += deg[i];
    part[t] = s;
    __syncthreads();
    for (int off = 1; off < SCAN_T; off <<= 1) {
        int v = (t >= off) ? part[t - off] : 0;
        __syncthreads();
        part[t] += v;
        __syncthreads();
    }
    int run = (t > 0) ? part[t - 1] : 0;
    for (int i = lo; i < hi; ++i) {
        offs[i] = run;
        cur[i]  = run;
        run += deg[i];
    }
    if (t == SCAN_T - 1) offs[NN] = run;
}

// ---------------------------------------------------------------------------
// K4: bucket edges. csr_r[row-bucket] = col ; csr_c[col-bucket] = row
// ---------------------------------------------------------------------------
__global__ void bucket_kernel(const int* __restrict__ ei, int* __restrict__ cur_r,
                              int* __restrict__ cur_c, int* __restrict__ csr_r,
                              int* __restrict__ csr_c) {
    int e = blockIdx.x * blockDim.x + threadIdx.x;
    if (e >= NE) return;
    int r = ei[e];
    int c = ei[NE + e];
    int p = atomicAdd(&cur_r[r], 1);
    csr_r[p] = c;
    int q = atomicAdd(&cur_c[c], 1);
    csr_c[q] = r;
}

// ---------------------------------------------------------------------------
// K5a: x f32 -> bf16 (for the gather's random reads)
// ---------------------------------------------------------------------------
__global__ void convert_x_kernel(const float* __restrict__ x, short* __restrict__ xbf) {
    int i = blockIdx.x * blockDim.x + threadIdx.x;
    if (i >= NN * NF / 8) return;
    float4 a = ((const float4*)x)[i * 2];
    float4 b = ((const float4*)x)[i * 2 + 1];
    bf16x8 v;
    v[0] = f2bf(a.x); v[1] = f2bf(a.y); v[2] = f2bf(a.z); v[3] = f2bf(a.w);
    v[4] = f2bf(b.x); v[5] = f2bf(b.y); v[6] = f2bf(b.z); v[7] = f2bf(b.w);
    *(bf16x8*)(xbf + i * 8) = v;
}

// ---------------------------------------------------------------------------
// K5b: 5 weight matrices f32 -> bf16 (stacked [5][128][128])
// ---------------------------------------------------------------------------
__global__ void convert_w_kernel(const float* __restrict__ g1, const float* __restrict__ g2,
                                 const float* __restrict__ b1, const float* __restrict__ b2,
                                 const float* __restrict__ lin, short* __restrict__ wbf) {
    int i = blockIdx.x * blockDim.x + threadIdx.x;
    if (i >= 5 * NF * NF) return;
    int m = i >> 14, off = i & (NF * NF - 1);
    float v = (m == 0) ? g1[off] : (m == 1) ? g2[off] : (m == 2) ? b1[off]
            : (m == 3) ? b2[off] : lin[off];
    wbf[i] = f2bf(v);
}

// ---------------------------------------------------------------------------
// K6: neighbor mean gather (bf16 payload). 16 lanes per node, 16 nodes/block.
// ---------------------------------------------------------------------------
__global__ __launch_bounds__(256) void gather_x_kernel(
    const int* __restrict__ offs_r, const int* __restrict__ csr_r,
    const short* __restrict__ xbf, short* __restrict__ nbbf) {
    int g = blockIdx.x * 16 + (threadIdx.x >> 4);
    int l = threadIdx.x & 15;
    if (g >= NN) return;
    int s = offs_r[g], e = offs_r[g + 1];
    float acc[8] = {0.f, 0.f, 0.f, 0.f, 0.f, 0.f, 0.f, 0.f};
    for (int j = s; j < e; ++j) {
        int src = csr_r[j];
        bf16x8 v = *(const bf16x8*)(xbf + src * NF + l * 8);
        #pragma unroll
        for (int k = 0; k < 8; ++k) acc[k] += bf2f(v[k]);
    }
    float inv = 1.0f / fmaxf((float)(e - s), 1.0f);
    bf16x8 o;
    #pragma unroll
    for (int k = 0; k < 8; ++k) o[k] = f2bf(acc[k] * inv);
    *(bf16x8*)(nbbf + g * NF + l * 8) = o;
}

// ---------------------------------------------------------------------------
// K7: fused FiLM (5 GEMMs) + h_s GEMM, all MFMA 16x16x32 bf16.
// Block = 256 thr = 4 waves, 64 nodes/block, wave w -> nodes w*16..w*16+15.
// Pass 1: acc_g = x@g1 + nb@g2 ; acc_b = x@b1 + nb@b2 ; acc_w = x@lin
//         output = x + (lrelu(acc_g)+1)*r + lrelu(acc_b) - nb -> d_out + os LDS
//         xws = dinv*acc_w (bf16)
// Pass 2: hsb = output @ lin^T + bias
// LDS tiles XOR-swizzled on 16B chunks: chunk c -> c ^ (row&7).
// ---------------------------------------------------------------------------
__global__ __launch_bounds__(256) void film_mfma_kernel(
    const float* __restrict__ x, const short* __restrict__ nbbf,
    const short* __restrict__ wbf, const float* __restrict__ rvec,
    const float* __restrict__ bias, const float* __restrict__ dinv,
    float* __restrict__ outp, short* __restrict__ xws, float* __restrict__ hsb) {
    __shared__ short xs[64 * NF];
    __shared__ short ns[64 * NF];
    __shared__ short os[64 * NF];

    const short* g1w  = wbf;
    const short* g2w  = wbf + 16384;
    const short* b1w  = wbf + 2 * 16384;
    const short* b2w  = wbf + 3 * 16384;
    const short* linw = wbf + 4 * 16384;

    int tid = threadIdx.x;
    int node0 = blockIdx.x * 64;

    // ---- stage x (f32->bf16) and nb into swizzled LDS ----
    #pragma unroll
    for (int it = 0; it < 4; ++it) {
        int chunk = it * 256 + tid;          // 0..1023
        int row = chunk >> 4;
        int c = chunk & 15;
        int grow = min(node0 + row, NN - 1);
        int swz = ((c ^ (row & 7)) << 3);
        float4 f0 = *(const float4*)(x + grow * NF + c * 8);
        float4 f1 = *(const float4*)(x + grow * NF + c * 8 + 4);
        bf16x8 v;
        v[0] = f2bf(f0.x); v[1] = f2bf(f0.y); v[2] = f2bf(f0.z); v[3] = f2bf(f0.w);
        v[4] = f2bf(f1.x); v[5] = f2bf(f1.y); v[6] = f2bf(f1.z); v[7] = f2bf(f1.w);
        *(bf16x8*)(xs + row * NF + swz) = v;
        *(bf16x8*)(ns + row * NF + swz) = *(const bf16x8*)(nbbf + grow * NF + c * 8);
    }
    __syncthreads();

    int w = tid >> 6;
    int l = tid & 63;
    int lr = l & 15;       // frag row/col lane index
    int lg = l >> 4;       // k-group 0..3
    int rowbase = w * 16;

    // ---- a-fragments: lane holds row (rowbase+lr), k = kb*32 + lg*8 .. +7 ----
    bf16x8 xf[4], nf[4];
    #pragma unroll
    for (int kb = 0; kb < 4; ++kb) {
        int row = rowbase + lr;
        int swz = (((kb * 4 + lg) ^ (row & 7)) << 3);
        xf[kb] = *(const bf16x8*)(xs + row * NF + swz);
        nf[kb] = *(const bf16x8*)(ns + row * NF + swz);
    }

    // dinv for this lane's 4 output rows
    float dv[4];
    #pragma unroll
    for (int q = 0; q < 4; ++q)
        dv[q] = dinv[min(node0 + rowbase + lg * 4 + q, NN - 1)];

    // ---- pass 1: 8 out-tiles of 16 features ----
    #pragma unroll 1
    for (int n0 = 0; n0 < 8; ++n0) {
        f32x4 ag = {0.f, 0.f, 0.f, 0.f};
        f32x4 ab = {0.f, 0.f, 0.f, 0.f};
        f32x4 aw = {0.f, 0.f, 0.f, 0.f};
        int wrow = (n0 * 16 + lr) * NF;
        #pragma unroll
        for (int kb = 0; kb < 4; ++kb) {
            int ko = kb * 32 + lg * 8;
            bf16x8 f1 = *(const bf16x8*)(g1w + wrow + ko);
            bf16x8 f2 = *(const bf16x8*)(g2w + wrow + ko);
            bf16x8 f3 = *(const bf16x8*)(b1w + wrow + ko);
            bf16x8 f4 = *(const bf16x8*)(b2w + wrow + ko);
            bf16x8 f5 = *(const bf16x8*)(linw + wrow + ko);
            ag = __builtin_amdgcn_mfma_f32_16x16x32_bf16(xf[kb], f1, ag, 0, 0, 0);
            ag = __builtin_amdgcn_mfma_f32_16x16x32_bf16(nf[kb], f2, ag, 0, 0, 0);
            ab = __builtin_amdgcn_mfma_f32_16x16x32_bf16(xf[kb], f3, ab, 0, 0, 0);
            ab = __builtin_amdgcn_mfma_f32_16x16x32_bf16(nf[kb], f4, ab, 0, 0, 0);
            aw = __builtin_amdgcn_mfma_f32_16x16x32_bf16(xf[kb], f5, aw, 0, 0, 0);
        }
        int col = n0 * 16 + lr;
        float rcol = rvec[col];
        #pragma unroll
        for (int q = 0; q < 4; ++q) {
            int nl = rowbase + lg * 4 + q;
            int ng = node0 + nl;
            int addr = nl * NF + (((col >> 3) ^ (nl & 7)) << 3) + (col & 7);
            float xv = bf2f(xs[addr]);
            float nv = bf2f(ns[addr]);
            float gp = ag[q], bp = ab[q];
            float gamma = (gp >= 0.f ? gp : 0.2f * gp) + 1.0f;
            float beta  = (bp >= 0.f ? bp : 0.2f * bp);
            float o = xv + gamma * rcol + beta - nv;
            os[addr] = f2bf(o);
            if (ng < NN) {
                outp[ng * NF + col] = o;
                xws[ng * NF + col]  = f2bf(dv[q] * aw[q]);
            }
        }
    }

    // ---- pass 2: hsb = output @ lin^T + bias (wave-local rows only) ----
    bf16x8 of[4];
    #pragma unroll
    for (int kb = 0; kb < 4; ++kb) {
        int row = rowbase + lr;
        int swz = (((kb * 4 + lg) ^ (row & 7)) << 3);
        of[kb] = *(const bf16x8*)(os + row * NF + swz);
    }
    #pragma unroll 1
    for (int n0 = 0; n0 < 8; ++n0) {
        f32x4 as = {0.f, 0.f, 0.f, 0.f};
        int wrow = (n0 * 16 + lr) * NF;
        #pragma unroll
        for (int kb = 0; kb < 4; ++kb) {
            bf16x8 f5 = *(const bf16x8*)(linw + wrow + kb * 32 + lg * 8);
            as = __builtin_amdgcn_mfma_f32_16x16x32_bf16(of[kb], f5, as, 0, 0, 0);
        }
        int col = n0 * 16 + lr;
        float bcol = bias[col];
        #pragma unroll
        for (int q = 0; q < 4; ++q) {
            int ng = node0 + rowbase + lg * 4 + q;
            if (ng < NN) hsb[ng * NF + col] = as[q] + bcol;
        }
    }
}

// ---------------------------------------------------------------------------
// K8: GCN gather + final combine:
// hko[c] = (dinv[c]*(sum_{r in in(c)} xws[r] + xws[c]) + hsb[c]) / (deg_r[c]+1)
// ---------------------------------------------------------------------------
__global__ __launch_bounds__(256) void gather_gcn_kernel(
    const int* __restrict__ offs_c, const int* __restrict__ csr_c,
    const short* __restrict__ xws, const float* __restrict__ dinv,
    const float* __restrict__ hsb, const int* __restrict__ deg_r,
    float* __restrict__ hko) {
    int g = blockIdx.x * 16 + (threadIdx.x >> 4);
    int l = threadIdx.x & 15;
    if (g >= NN) return;
    int s = offs_c[g], e = offs_c[g + 1];
    float acc[8];
    bf16x8 self = *(const bf16x8*)(xws + g * NF + l * 8);
    #pragma unroll
    for (int k = 0; k < 8; ++k) acc[k] = bf2f(self[k]);
    for (int j = s; j < e; ++j) {
        int src = csr_c[j];
        bf16x8 v = *(const bf16x8*)(xws + src * NF + l * 8);
        #pragma unroll
        for (int k = 0; k < 8; ++k) acc[k] += bf2f(v[k]);
    }
    float dc = dinv[g];
    float invd = 1.0f / ((float)deg_r[g] + 1.0f);
    float4 h0 = *(const float4*)(hsb + g * NF + l * 8);
    float4 h1 = *(const float4*)(hsb + g * NF + l * 8 + 4);
    float4 o0, o1;
    o0.x = (dc * acc[0] + h0.x) * invd;
    o0.y = (dc * acc[1] + h0.y) * invd;
    o0.z = (dc * acc[2] + h0.z) * invd;
    o0.w = (dc * acc[3] + h0.w) * invd;
    o1.x = (dc * acc[4] + h1.x) * invd;
    o1.y = (dc * acc[5] + h1.y) * invd;
    o1.z = (dc * acc[6] + h1.z) * invd;
    o1.w = (dc * acc[7] + h1.w) * invd;
    *(float4*)(hko + g * NF + l * 8) = o0;
    *(float4*)(hko + g * NF + l * 8 + 4) = o1;
}

// ---------------------------------------------------------------------------
extern "C" void kernel_launch(void* const* d_in, const int* in_sizes, int n_in,
                              void* d_out, int out_size, void* d_ws, size_t ws_size,
                              hipStream_t stream) {
    const float* x    = (const float*)d_in[0];
    const int*   ei   = (const int*)d_in[1];
    const float* g1   = (const float*)d_in[3];
    const float* g2   = (const float*)d_in[4];
    const float* b1   = (const float*)d_in[5];
    const float* b2   = (const float*)d_in[6];
    const float* rv   = (const float*)d_in[7];
    const float* lin  = (const float*)d_in[8];
    const float* bias = (const float*)d_in[9];

    float* hsb  = (float*)d_ws;                  // N*F f32
    float* dinv = hsb + NN * NF;                 // N
    int* deg_r  = (int*)(dinv + NN);             // N (zeroed)
    int* deg_c  = deg_r + NN;                    // N (zeroed)
    int* cur_r  = deg_c + NN;                    // N
    int* cur_c  = cur_r + NN;                    // N
    int* csr_r  = cur_c + NN;                    // E
    int* csr_c  = csr_r + NE;                    // E
    int* offs_r = csr_c + NE;                    // N+1
    int* offs_c = offs_r + (NN + 1);             // N+1
    uintptr_t p = (uintptr_t)(offs_c + NN + 1);
    p = (p + 15) & ~(uintptr_t)15;
    short* xbf  = (short*)p;                     // N*F bf16
    short* nbbf = xbf + NN * NF;                 // N*F bf16
    short* xws  = nbbf + NN * NF;                // N*F bf16
    short* wbf  = xws + NN * NF;                 // 5*128*128 bf16

    float* hko  = (float*)d_out;                 // N*F (h_k)
    float* outp = hko + NN * NF;                 // N*F (output)

    hipMemsetAsync(deg_r, 0, 2 * NN * sizeof(int), stream);

    degree_kernel<<<(NE + 255) / 256, 256, 0, stream>>>(ei, deg_r, deg_c);
    dinv_kernel<<<(NN + 255) / 256, 256, 0, stream>>>(deg_c, dinv);
    scan_kernel<<<2, SCAN_T, 0, stream>>>(deg_r, deg_c, offs_r, offs_c, cur_r, cur_c);
    bucket_kernel<<<(NE + 255) / 256, 256, 0, stream>>>(ei, cur_r, cur_c, csr_r, csr_c);
    convert_x_kernel<<<(NN * NF / 8 + 255) / 256, 256, 0, stream>>>(x, xbf);
    convert_w_kernel<<<(5 * NF * NF + 255) / 256, 256, 0, stream>>>(g1, g2, b1, b2, lin, wbf);
    gather_x_kernel<<<(NN + 15) / 16, 256, 0, stream>>>(offs_r, csr_r, xbf, nbbf);
    film_mfma_kernel<<<(NN + 63) / 64, 256, 0, stream>>>(x, nbbf, wbf, rv, bias, dinv,
                                                         outp, xws, hsb);
    gather_gcn_kernel<<<(NN + 15) / 16, 256, 0, stream>>>(offs_c, csr_c, xws, dinv,
                                                          hsb, deg_r, hko);
}

// Round 4
// 260.963 us; speedup vs baseline: 12.0777x; 1.9452x over previous
//
#include <hip/hip_runtime.h>

#define NN 50000
#define NE 800000
#define NF 128

#define SHIFT 8
#define NB 196            // ceil(50000/256)
#define PBLOCKS 128
#define PCHUNK ((NE + PBLOCKS - 1) / PBLOCKS)   // 6250

typedef __attribute__((ext_vector_type(4))) float f32x4;
typedef __attribute__((ext_vector_type(8))) short bf16x8;

__device__ __forceinline__ short f2bf(float f) {
    unsigned u = __float_as_uint(f);
    u += 0x7FFF + ((u >> 16) & 1);      // round-to-nearest-even
    return (short)(u >> 16);
}
__device__ __forceinline__ float bf2f(short s) {
    return __uint_as_float(((unsigned)(unsigned short)s) << 16);
}

// ---------------------------------------------------------------------------
// P0: count edges per coarse bucket (row side and col side) via LDS counters
// ---------------------------------------------------------------------------
__global__ __launch_bounds__(256) void p0_count_kernel(const int* __restrict__ ei,
                                                       int* __restrict__ gcnt) {
    __shared__ int cnt[2 * NB];
    int t = threadIdx.x;
    for (int i = t; i < 2 * NB; i += 256) cnt[i] = 0;
    __syncthreads();
    int lo = blockIdx.x * PCHUNK;
    int hi = min(lo + PCHUNK, NE);
    for (int j = lo + t; j < hi; j += 256) {
        int r = ei[j];
        int c = ei[NE + j];
        atomicAdd(&cnt[r >> SHIFT], 1);
        atomicAdd(&cnt[NB + (c >> SHIFT)], 1);
    }
    __syncthreads();
    for (int i = t; i < 2 * NB; i += 256)
        if (cnt[i]) atomicAdd(&gcnt[i], cnt[i]);
}

// ---------------------------------------------------------------------------
// P1: scan bucket counts -> bases + cursors (one block)
// ---------------------------------------------------------------------------
__global__ __launch_bounds__(256) void p1_scan_kernel(const int* __restrict__ gcnt,
                                                      int* __restrict__ baseR,
                                                      int* __restrict__ baseC,
                                                      int* __restrict__ gcur) {
    __shared__ int s[256];
    int t = threadIdx.x;
    // ---- row side ----
    int v = (t < NB) ? gcnt[t] : 0;
    s[t] = v;
    __syncthreads();
    for (int off = 1; off < 256; off <<= 1) {
        int u = (t >= off) ? s[t - off] : 0;
        __syncthreads();
        s[t] += u;
        __syncthreads();
    }
    if (t < NB) {
        int excl = s[t] - v;
        baseR[t] = excl;
        gcur[t] = excl;
        if (t == NB - 1) baseR[NB] = s[t];
    }
    __syncthreads();
    // ---- col side ----
    int v2 = (t < NB) ? gcnt[NB + t] : 0;
    s[t] = v2;
    __syncthreads();
    for (int off = 1; off < 256; off <<= 1) {
        int u = (t >= off) ? s[t - off] : 0;
        __syncthreads();
        s[t] += u;
        __syncthreads();
    }
    if (t < NB) {
        int excl = s[t] - v2;
        baseC[t] = excl;
        gcur[NB + t] = excl;
        if (t == NB - 1) baseC[NB] = s[t];
    }
}

// ---------------------------------------------------------------------------
// P2: partition edges into bucket-contiguous arrays, 4B packed entries:
//     entry = (local_key << 17) | payload   (key = node & 255, payload = other node)
// ---------------------------------------------------------------------------
__global__ __launch_bounds__(256) void p2_partition_kernel(const int* __restrict__ ei,
                                                           int* __restrict__ gcur,
                                                           unsigned* __restrict__ partR,
                                                           unsigned* __restrict__ partC) {
    __shared__ int cnt[2 * NB];
    __shared__ int res[2 * NB];
    int t = threadIdx.x;
    for (int i = t; i < 2 * NB; i += 256) cnt[i] = 0;
    __syncthreads();
    int lo = blockIdx.x * PCHUNK;
    int hi = min(lo + PCHUNK, NE);
    for (int j = lo + t; j < hi; j += 256) {
        int r = ei[j];
        int c = ei[NE + j];
        atomicAdd(&cnt[r >> SHIFT], 1);
        atomicAdd(&cnt[NB + (c >> SHIFT)], 1);
    }
    __syncthreads();
    for (int i = t; i < 2 * NB; i += 256) {
        int n = cnt[i];
        res[i] = n ? atomicAdd(&gcur[i], n) : 0;
        cnt[i] = 0;
    }
    __syncthreads();
    for (int j = lo + t; j < hi; j += 256) {
        int r = ei[j];
        int c = ei[NE + j];
        int bR = r >> SHIFT;
        int sR = atomicAdd(&cnt[bR], 1);
        partR[res[bR] + sR] = ((unsigned)(r & 255) << 17) | (unsigned)c;
        int bC = NB + (c >> SHIFT);
        int sC = atomicAdd(&cnt[bC], 1);
        partC[res[bC] + sC] = ((unsigned)(c & 255) << 17) | (unsigned)r;
    }
}

// ---------------------------------------------------------------------------
// P3: per (side,bucket): degree count -> scan -> offs/deg/dinv -> place CSR
// ---------------------------------------------------------------------------
__global__ __launch_bounds__(256) void p3_build_kernel(
    const unsigned* __restrict__ partR, const unsigned* __restrict__ partC,
    const int* __restrict__ baseR, const int* __restrict__ baseC,
    int* __restrict__ offs_r, int* __restrict__ offs_c,
    int* __restrict__ csr_r, int* __restrict__ csr_c,
    int* __restrict__ degr, float* __restrict__ dinv) {
    int side = blockIdx.x / NB;
    int b = blockIdx.x - side * NB;
    const unsigned* part = side ? partC : partR;
    const int* base = side ? baseC : baseR;
    int* offs = side ? offs_c : offs_r;
    int* csr = side ? csr_c : csr_r;

    __shared__ int deg[256];
    __shared__ int cur[256];
    int t = threadIdx.x;
    int s0 = base[b], s1 = base[b + 1];
    deg[t] = 0;
    __syncthreads();
    for (int j = s0 + t; j < s1; j += 256)
        atomicAdd(&deg[part[j] >> 17], 1);
    __syncthreads();
    int myDeg = deg[t];
    // inclusive scan over 256
    for (int off = 1; off < 256; off <<= 1) {
        int u = (t >= off) ? deg[t - off] : 0;
        __syncthreads();
        deg[t] += u;
        __syncthreads();
    }
    int excl = deg[t] - myDeg;
    int node = (b << SHIFT) + t;
    if (node <= NN) offs[node] = s0 + excl;     // node==NN writes the sentinel (==s1)
    if (node < NN) {
        if (side == 0) degr[node] = myDeg;
        else           dinv[node] = rsqrtf((float)myDeg + 1.0f);
    }
    cur[t] = excl;
    __syncthreads();
    for (int j = s0 + t; j < s1; j += 256) {
        unsigned en = part[j];
        int k = en >> 17;
        int p = atomicAdd(&cur[k], 1);
        csr[s0 + p] = (int)(en & 0x1FFFFu);
    }
}

// ---------------------------------------------------------------------------
// K5a: x f32 -> bf16 (for the gather's random reads)
// ---------------------------------------------------------------------------
__global__ void convert_x_kernel(const float* __restrict__ x, short* __restrict__ xbf) {
    int i = blockIdx.x * blockDim.x + threadIdx.x;
    if (i >= NN * NF / 8) return;
    float4 a = ((const float4*)x)[i * 2];
    float4 b = ((const float4*)x)[i * 2 + 1];
    bf16x8 v;
    v[0] = f2bf(a.x); v[1] = f2bf(a.y); v[2] = f2bf(a.z); v[3] = f2bf(a.w);
    v[4] = f2bf(b.x); v[5] = f2bf(b.y); v[6] = f2bf(b.z); v[7] = f2bf(b.w);
    *(bf16x8*)(xbf + i * 8) = v;
}

// ---------------------------------------------------------------------------
// K5b: 5 weight matrices f32 -> bf16 (stacked [5][128][128])
// ---------------------------------------------------------------------------
__global__ void convert_w_kernel(const float* __restrict__ g1, const float* __restrict__ g2,
                                 const float* __restrict__ b1, const float* __restrict__ b2,
                                 const float* __restrict__ lin, short* __restrict__ wbf) {
    int i = blockIdx.x * blockDim.x + threadIdx.x;
    if (i >= 5 * NF * NF) return;
    int m = i >> 14, off = i & (NF * NF - 1);
    float v = (m == 0) ? g1[off] : (m == 1) ? g2[off] : (m == 2) ? b1[off]
            : (m == 3) ? b2[off] : lin[off];
    wbf[i] = f2bf(v);
}

// ---------------------------------------------------------------------------
// K6: neighbor mean gather (bf16 payload). 16 lanes per node, 16 nodes/block.
// ---------------------------------------------------------------------------
__global__ __launch_bounds__(256) void gather_x_kernel(
    const int* __restrict__ offs_r, const int* __restrict__ csr_r,
    const short* __restrict__ xbf, short* __restrict__ nbbf) {
    int g = blockIdx.x * 16 + (threadIdx.x >> 4);
    int l = threadIdx.x & 15;
    if (g >= NN) return;
    int s = offs_r[g], e = offs_r[g + 1];
    float acc[8] = {0.f, 0.f, 0.f, 0.f, 0.f, 0.f, 0.f, 0.f};
    for (int j = s; j < e; ++j) {
        int src = csr_r[j];
        bf16x8 v = *(const bf16x8*)(xbf + src * NF + l * 8);
        #pragma unroll
        for (int k = 0; k < 8; ++k) acc[k] += bf2f(v[k]);
    }
    float inv = 1.0f / fmaxf((float)(e - s), 1.0f);
    bf16x8 o;
    #pragma unroll
    for (int k = 0; k < 8; ++k) o[k] = f2bf(acc[k] * inv);
    *(bf16x8*)(nbbf + g * NF + l * 8) = o;
}

// ---------------------------------------------------------------------------
// K7: fused FiLM (5 GEMMs) + h_s GEMM, all MFMA 16x16x32 bf16.
// ---------------------------------------------------------------------------
__global__ __launch_bounds__(256) void film_mfma_kernel(
    const float* __restrict__ x, const short* __restrict__ nbbf,
    const short* __restrict__ wbf, const float* __restrict__ rvec,
    const float* __restrict__ bias, const float* __restrict__ dinv,
    float* __restrict__ outp, short* __restrict__ xws, float* __restrict__ hsb) {
    __shared__ short xs[64 * NF];
    __shared__ short ns[64 * NF];
    __shared__ short os[64 * NF];

    const short* g1w  = wbf;
    const short* g2w  = wbf + 16384;
    const short* b1w  = wbf + 2 * 16384;
    const short* b2w  = wbf + 3 * 16384;
    const short* linw = wbf + 4 * 16384;

    int tid = threadIdx.x;
    int node0 = blockIdx.x * 64;

    #pragma unroll
    for (int it = 0; it < 4; ++it) {
        int chunk = it * 256 + tid;          // 0..1023
        int row = chunk >> 4;
        int c = chunk & 15;
        int grow = min(node0 + row, NN - 1);
        int swz = ((c ^ (row & 7)) << 3);
        float4 f0 = *(const float4*)(x + grow * NF + c * 8);
        float4 f1 = *(const float4*)(x + grow * NF + c * 8 + 4);
        bf16x8 v;
        v[0] = f2bf(f0.x); v[1] = f2bf(f0.y); v[2] = f2bf(f0.z); v[3] = f2bf(f0.w);
        v[4] = f2bf(f1.x); v[5] = f2bf(f1.y); v[6] = f2bf(f1.z); v[7] = f2bf(f1.w);
        *(bf16x8*)(xs + row * NF + swz) = v;
        *(bf16x8*)(ns + row * NF + swz) = *(const bf16x8*)(nbbf + grow * NF + c * 8);
    }
    __syncthreads();

    int w = tid >> 6;
    int l = tid & 63;
    int lr = l & 15;
    int lg = l >> 4;
    int rowbase = w * 16;

    bf16x8 xf[4], nf[4];
    #pragma unroll
    for (int kb = 0; kb < 4; ++kb) {
        int row = rowbase + lr;
        int swz = (((kb * 4 + lg) ^ (row & 7)) << 3);
        xf[kb] = *(const bf16x8*)(xs + row * NF + swz);
        nf[kb] = *(const bf16x8*)(ns + row * NF + swz);
    }

    float dv[4];
    #pragma unroll
    for (int q = 0; q < 4; ++q)
        dv[q] = dinv[min(node0 + rowbase + lg * 4 + q, NN - 1)];

    #pragma unroll 1
    for (int n0 = 0; n0 < 8; ++n0) {
        f32x4 ag = {0.f, 0.f, 0.f, 0.f};
        f32x4 ab = {0.f, 0.f, 0.f, 0.f};
        f32x4 aw = {0.f, 0.f, 0.f, 0.f};
        int wrow = (n0 * 16 + lr) * NF;
        #pragma unroll
        for (int kb = 0; kb < 4; ++kb) {
            int ko = kb * 32 + lg * 8;
            bf16x8 f1 = *(const bf16x8*)(g1w + wrow + ko);
            bf16x8 f2 = *(const bf16x8*)(g2w + wrow + ko);
            bf16x8 f3 = *(const bf16x8*)(b1w + wrow + ko);
            bf16x8 f4 = *(const bf16x8*)(b2w + wrow + ko);
            bf16x8 f5 = *(const bf16x8*)(linw + wrow + ko);
            ag = __builtin_amdgcn_mfma_f32_16x16x32_bf16(xf[kb], f1, ag, 0, 0, 0);
            ag = __builtin_amdgcn_mfma_f32_16x16x32_bf16(nf[kb], f2, ag, 0, 0, 0);
            ab = __builtin_amdgcn_mfma_f32_16x16x32_bf16(xf[kb], f3, ab, 0, 0, 0);
            ab = __builtin_amdgcn_mfma_f32_16x16x32_bf16(nf[kb], f4, ab, 0, 0, 0);
            aw = __builtin_amdgcn_mfma_f32_16x16x32_bf16(xf[kb], f5, aw, 0, 0, 0);
        }
        int col = n0 * 16 + lr;
        float rcol = rvec[col];
        #pragma unroll
        for (int q = 0; q < 4; ++q) {
            int nl = rowbase + lg * 4 + q;
            int ng = node0 + nl;
            int addr = nl * NF + (((col >> 3) ^ (nl & 7)) << 3) + (col & 7);
            float xv = bf2f(xs[addr]);
            float nv = bf2f(ns[addr]);
            float gp = ag[q], bp = ab[q];
            float gamma = (gp >= 0.f ? gp : 0.2f * gp) + 1.0f;
            float beta  = (bp >= 0.f ? bp : 0.2f * bp);
            float o = xv + gamma * rcol + beta - nv;
            os[addr] = f2bf(o);
            if (ng < NN) {
                outp[ng * NF + col] = o;
                xws[ng * NF + col]  = f2bf(dv[q] * aw[q]);
            }
        }
    }

    bf16x8 of[4];
    #pragma unroll
    for (int kb = 0; kb < 4; ++kb) {
        int row = rowbase + lr;
        int swz = (((kb * 4 + lg) ^ (row & 7)) << 3);
        of[kb] = *(const bf16x8*)(os + row * NF + swz);
    }
    #pragma unroll 1
    for (int n0 = 0; n0 < 8; ++n0) {
        f32x4 as = {0.f, 0.f, 0.f, 0.f};
        int wrow = (n0 * 16 + lr) * NF;
        #pragma unroll
        for (int kb = 0; kb < 4; ++kb) {
            bf16x8 f5 = *(const bf16x8*)(linw + wrow + kb * 32 + lg * 8);
            as = __builtin_amdgcn_mfma_f32_16x16x32_bf16(of[kb], f5, as, 0, 0, 0);
        }
        int col = n0 * 16 + lr;
        float bcol = bias[col];
        #pragma unroll
        for (int q = 0; q < 4; ++q) {
            int ng = node0 + rowbase + lg * 4 + q;
            if (ng < NN) hsb[ng * NF + col] = as[q] + bcol;
        }
    }
}

// ---------------------------------------------------------------------------
// K8: GCN gather + final combine
// ---------------------------------------------------------------------------
__global__ __launch_bounds__(256) void gather_gcn_kernel(
    const int* __restrict__ offs_c, const int* __restrict__ csr_c,
    const short* __restrict__ xws, const float* __restrict__ dinv,
    const float* __restrict__ hsb, const int* __restrict__ degr,
    float* __restrict__ hko) {
    int g = blockIdx.x * 16 + (threadIdx.x >> 4);
    int l = threadIdx.x & 15;
    if (g >= NN) return;
    int s = offs_c[g], e = offs_c[g + 1];
    float acc[8];
    bf16x8 self = *(const bf16x8*)(xws + g * NF + l * 8);
    #pragma unroll
    for (int k = 0; k < 8; ++k) acc[k] = bf2f(self[k]);
    for (int j = s; j < e; ++j) {
        int src = csr_c[j];
        bf16x8 v = *(const bf16x8*)(xws + src * NF + l * 8);
        #pragma unroll
        for (int k = 0; k < 8; ++k) acc[k] += bf2f(v[k]);
    }
    float dc = dinv[g];
    float invd = 1.0f / ((float)degr[g] + 1.0f);
    float4 h0 = *(const float4*)(hsb + g * NF + l * 8);
    float4 h1 = *(const float4*)(hsb + g * NF + l * 8 + 4);
    float4 o0, o1;
    o0.x = (dc * acc[0] + h0.x) * invd;
    o0.y = (dc * acc[1] + h0.y) * invd;
    o0.z = (dc * acc[2] + h0.z) * invd;
    o0.w = (dc * acc[3] + h0.w) * invd;
    o1.x = (dc * acc[4] + h1.x) * invd;
    o1.y = (dc * acc[5] + h1.y) * invd;
    o1.z = (dc * acc[6] + h1.z) * invd;
    o1.w = (dc * acc[7] + h1.w) * invd;
    *(float4*)(hko + g * NF + l * 8) = o0;
    *(float4*)(hko + g * NF + l * 8 + 4) = o1;
}

// ---------------------------------------------------------------------------
extern "C" void kernel_launch(void* const* d_in, const int* in_sizes, int n_in,
                              void* d_out, int out_size, void* d_ws, size_t ws_size,
                              hipStream_t stream) {
    const float* x    = (const float*)d_in[0];
    const int*   ei   = (const int*)d_in[1];
    const float* g1   = (const float*)d_in[3];
    const float* g2   = (const float*)d_in[4];
    const float* b1   = (const float*)d_in[5];
    const float* b2   = (const float*)d_in[6];
    const float* rv   = (const float*)d_in[7];
    const float* lin  = (const float*)d_in[8];
    const float* bias = (const float*)d_in[9];

    float* hsb  = (float*)d_ws;                  // N*F f32
    float* dinv = hsb + NN * NF;                 // N
    int* degr   = (int*)(dinv + NN);             // N
    int* offs_r = degr + NN;                     // N+1
    int* offs_c = offs_r + (NN + 1);             // N+1
    int* csr_r  = offs_c + (NN + 1);             // E
    int* csr_c  = csr_r + NE;                    // E
    unsigned* partR = (unsigned*)(csr_c + NE);   // E
    unsigned* partC = partR + NE;                // E
    int* gcnt   = (int*)(partC + NE);            // 2*NB (zeroed)
    int* gcur   = gcnt + 2 * NB;                 // 2*NB
    int* baseR  = gcur + 2 * NB;                 // NB+1
    int* baseC  = baseR + (NB + 1);              // NB+1
    uintptr_t p = (uintptr_t)(baseC + NB + 1);
    p = (p + 15) & ~(uintptr_t)15;
    short* xbf  = (short*)p;                     // N*F bf16
    short* nbbf = xbf + NN * NF;                 // N*F bf16
    short* xws  = nbbf + NN * NF;                // N*F bf16
    short* wbf  = xws + NN * NF;                 // 5*128*128 bf16

    float* hko  = (float*)d_out;                 // N*F (h_k)
    float* outp = hko + NN * NF;                 // N*F (output)

    hipMemsetAsync(gcnt, 0, 2 * NB * sizeof(int), stream);

    p0_count_kernel<<<PBLOCKS, 256, 0, stream>>>(ei, gcnt);
    p1_scan_kernel<<<1, 256, 0, stream>>>(gcnt, baseR, baseC, gcur);
    p2_partition_kernel<<<PBLOCKS, 256, 0, stream>>>(ei, gcur, partR, partC);
    p3_build_kernel<<<2 * NB, 256, 0, stream>>>(partR, partC, baseR, baseC,
                                                offs_r, offs_c, csr_r, csr_c, degr, dinv);
    convert_x_kernel<<<(NN * NF / 8 + 255) / 256, 256, 0, stream>>>(x, xbf);
    convert_w_kernel<<<(5 * NF * NF + 255) / 256, 256, 0, stream>>>(g1, g2, b1, b2, lin, wbf);
    gather_x_kernel<<<(NN + 15) / 16, 256, 0, stream>>>(offs_r, csr_r, xbf, nbbf);
    film_mfma_kernel<<<(NN + 63) / 64, 256, 0, stream>>>(x, nbbf, wbf, rv, bias, dinv,
                                                         outp, xws, hsb);
    gather_gcn_kernel<<<(NN + 15) / 16, 256, 0, stream>>>(offs_c, csr_c, xws, dinv,
                                                          hsb, degr, hko);
}

// Round 5
// 246.523 us; speedup vs baseline: 12.7851x; 1.0586x over previous
//
#include <hip/hip_runtime.h>

#define NN 50000
#define NE 800000
#define NF 128

#define SHIFT 8
#define NB 196            // ceil(50000/256)
#define PBLOCKS 128
#define PCHUNK ((NE + PBLOCKS - 1) / PBLOCKS)   // 6250

typedef __attribute__((ext_vector_type(4))) float f32x4;
typedef __attribute__((ext_vector_type(8))) short bf16x8;

__device__ __forceinline__ short f2bf(float f) {
    unsigned u = __float_as_uint(f);
    u += 0x7FFF + ((u >> 16) & 1);      // round-to-nearest-even
    return (short)(u >> 16);
}
__device__ __forceinline__ float bf2f(short s) {
    return __uint_as_float(((unsigned)(unsigned short)s) << 16);
}

// ---------------------------------------------------------------------------
// P0: count edges per coarse bucket (row side and col side) via LDS counters
// ---------------------------------------------------------------------------
__global__ __launch_bounds__(256) void p0_count_kernel(const int* __restrict__ ei,
                                                       int* __restrict__ gcnt) {
    __shared__ int cnt[2 * NB];
    int t = threadIdx.x;
    for (int i = t; i < 2 * NB; i += 256) cnt[i] = 0;
    __syncthreads();
    int lo = blockIdx.x * PCHUNK;
    int hi = min(lo + PCHUNK, NE);
    for (int j = lo + t; j < hi; j += 256) {
        int r = ei[j];
        int c = ei[NE + j];
        atomicAdd(&cnt[r >> SHIFT], 1);
        atomicAdd(&cnt[NB + (c >> SHIFT)], 1);
    }
    __syncthreads();
    for (int i = t; i < 2 * NB; i += 256)
        if (cnt[i]) atomicAdd(&gcnt[i], cnt[i]);
}

// ---------------------------------------------------------------------------
// P1: scan bucket counts -> bases + cursors (one block)
// ---------------------------------------------------------------------------
__global__ __launch_bounds__(256) void p1_scan_kernel(const int* __restrict__ gcnt,
                                                      int* __restrict__ baseR,
                                                      int* __restrict__ baseC,
                                                      int* __restrict__ gcur) {
    __shared__ int s[256];
    int t = threadIdx.x;
    int v = (t < NB) ? gcnt[t] : 0;
    s[t] = v;
    __syncthreads();
    for (int off = 1; off < 256; off <<= 1) {
        int u = (t >= off) ? s[t - off] : 0;
        __syncthreads();
        s[t] += u;
        __syncthreads();
    }
    if (t < NB) {
        int excl = s[t] - v;
        baseR[t] = excl;
        gcur[t] = excl;
        if (t == NB - 1) baseR[NB] = s[t];
    }
    __syncthreads();
    int v2 = (t < NB) ? gcnt[NB + t] : 0;
    s[t] = v2;
    __syncthreads();
    for (int off = 1; off < 256; off <<= 1) {
        int u = (t >= off) ? s[t - off] : 0;
        __syncthreads();
        s[t] += u;
        __syncthreads();
    }
    if (t < NB) {
        int excl = s[t] - v2;
        baseC[t] = excl;
        gcur[NB + t] = excl;
        if (t == NB - 1) baseC[NB] = s[t];
    }
}

// ---------------------------------------------------------------------------
// P2: partition edges into bucket-contiguous arrays, 4B packed entries:
//     entry = (local_key << 17) | payload
// ---------------------------------------------------------------------------
__global__ __launch_bounds__(256) void p2_partition_kernel(const int* __restrict__ ei,
                                                           int* __restrict__ gcur,
                                                           unsigned* __restrict__ partR,
                                                           unsigned* __restrict__ partC) {
    __shared__ int cnt[2 * NB];
    __shared__ int res[2 * NB];
    int t = threadIdx.x;
    for (int i = t; i < 2 * NB; i += 256) cnt[i] = 0;
    __syncthreads();
    int lo = blockIdx.x * PCHUNK;
    int hi = min(lo + PCHUNK, NE);
    for (int j = lo + t; j < hi; j += 256) {
        int r = ei[j];
        int c = ei[NE + j];
        atomicAdd(&cnt[r >> SHIFT], 1);
        atomicAdd(&cnt[NB + (c >> SHIFT)], 1);
    }
    __syncthreads();
    for (int i = t; i < 2 * NB; i += 256) {
        int n = cnt[i];
        res[i] = n ? atomicAdd(&gcur[i], n) : 0;
        cnt[i] = 0;
    }
    __syncthreads();
    for (int j = lo + t; j < hi; j += 256) {
        int r = ei[j];
        int c = ei[NE + j];
        int bR = r >> SHIFT;
        int sR = atomicAdd(&cnt[bR], 1);
        partR[res[bR] + sR] = ((unsigned)(r & 255) << 17) | (unsigned)c;
        int bC = NB + (c >> SHIFT);
        int sC = atomicAdd(&cnt[bC], 1);
        partC[res[bC] + sC] = ((unsigned)(c & 255) << 17) | (unsigned)r;
    }
}

// ---------------------------------------------------------------------------
// P3: per (side,bucket): degree count -> scan -> offs/deg/dinv -> place CSR
// ---------------------------------------------------------------------------
__global__ __launch_bounds__(256) void p3_build_kernel(
    const unsigned* __restrict__ partR, const unsigned* __restrict__ partC,
    const int* __restrict__ baseR, const int* __restrict__ baseC,
    int* __restrict__ offs_r, int* __restrict__ offs_c,
    int* __restrict__ csr_r, int* __restrict__ csr_c,
    int* __restrict__ degr, float* __restrict__ dinv) {
    int side = blockIdx.x / NB;
    int b = blockIdx.x - side * NB;
    const unsigned* part = side ? partC : partR;
    const int* base = side ? baseC : baseR;
    int* offs = side ? offs_c : offs_r;
    int* csr = side ? csr_c : csr_r;

    __shared__ int deg[256];
    __shared__ int cur[256];
    int t = threadIdx.x;
    int s0 = base[b], s1 = base[b + 1];
    deg[t] = 0;
    __syncthreads();
    for (int j = s0 + t; j < s1; j += 256)
        atomicAdd(&deg[part[j] >> 17], 1);
    __syncthreads();
    int myDeg = deg[t];
    for (int off = 1; off < 256; off <<= 1) {
        int u = (t >= off) ? deg[t - off] : 0;
        __syncthreads();
        deg[t] += u;
        __syncthreads();
    }
    int excl = deg[t] - myDeg;
    int node = (b << SHIFT) + t;
    if (node <= NN) offs[node] = s0 + excl;
    if (node < NN) {
        if (side == 0) degr[node] = myDeg;
        else           dinv[node] = rsqrtf((float)myDeg + 1.0f);
    }
    cur[t] = excl;
    __syncthreads();
    for (int j = s0 + t; j < s1; j += 256) {
        unsigned en = part[j];
        int k = en >> 17;
        int p = atomicAdd(&cur[k], 1);
        csr[s0 + p] = (int)(en & 0x1FFFFu);
    }
}

// ---------------------------------------------------------------------------
// K5a: x f32 -> bf16
// ---------------------------------------------------------------------------
__global__ void convert_x_kernel(const float* __restrict__ x, short* __restrict__ xbf) {
    int i = blockIdx.x * blockDim.x + threadIdx.x;
    if (i >= NN * NF / 8) return;
    float4 a = ((const float4*)x)[i * 2];
    float4 b = ((const float4*)x)[i * 2 + 1];
    bf16x8 v;
    v[0] = f2bf(a.x); v[1] = f2bf(a.y); v[2] = f2bf(a.z); v[3] = f2bf(a.w);
    v[4] = f2bf(b.x); v[5] = f2bf(b.y); v[6] = f2bf(b.z); v[7] = f2bf(b.w);
    *(bf16x8*)(xbf + i * 8) = v;
}

// ---------------------------------------------------------------------------
// K5b: 5 weight matrices f32 -> bf16 (stacked [5][128][128])
// ---------------------------------------------------------------------------
__global__ void convert_w_kernel(const float* __restrict__ g1, const float* __restrict__ g2,
                                 const float* __restrict__ b1, const float* __restrict__ b2,
                                 const float* __restrict__ lin, short* __restrict__ wbf) {
    int i = blockIdx.x * blockDim.x + threadIdx.x;
    if (i >= 5 * NF * NF) return;
    int m = i >> 14, off = i & (NF * NF - 1);
    float v = (m == 0) ? g1[off] : (m == 1) ? g2[off] : (m == 2) ? b1[off]
            : (m == 3) ? b2[off] : lin[off];
    wbf[i] = f2bf(v);
}

// ---------------------------------------------------------------------------
// K6: neighbor mean gather (bf16 payload), unroll-2 for MLP.
// ---------------------------------------------------------------------------
__global__ __launch_bounds__(256) void gather_x_kernel(
    const int* __restrict__ offs_r, const int* __restrict__ csr_r,
    const short* __restrict__ xbf, short* __restrict__ nbbf) {
    int g = blockIdx.x * 16 + (threadIdx.x >> 4);
    int l = threadIdx.x & 15;
    if (g >= NN) return;
    int s = offs_r[g], e = offs_r[g + 1];
    float acc[8] = {0.f, 0.f, 0.f, 0.f, 0.f, 0.f, 0.f, 0.f};
    int j = s;
    for (; j + 2 <= e; j += 2) {
        int s0 = csr_r[j], s1 = csr_r[j + 1];
        bf16x8 v0 = *(const bf16x8*)(xbf + s0 * NF + l * 8);
        bf16x8 v1 = *(const bf16x8*)(xbf + s1 * NF + l * 8);
        #pragma unroll
        for (int k = 0; k < 8; ++k) acc[k] += bf2f(v0[k]) + bf2f(v1[k]);
    }
    if (j < e) {
        bf16x8 v = *(const bf16x8*)(xbf + csr_r[j] * NF + l * 8);
        #pragma unroll
        for (int k = 0; k < 8; ++k) acc[k] += bf2f(v[k]);
    }
    float inv = 1.0f / fmaxf((float)(e - s), 1.0f);
    bf16x8 o;
    #pragma unroll
    for (int k = 0; k < 8; ++k) o[k] = f2bf(acc[k] * inv);
    *(bf16x8*)(nbbf + g * NF + l * 8) = o;
}

// ---------------------------------------------------------------------------
// K7: fused FiLM (5 GEMMs) + h_s GEMM, all MFMA 16x16x32 bf16.
// LDS: xs + ns only (32 KB); output is written back INTO xs in the pass-1
// epilogue (each lane reads xs/ns at addr then overwrites xs at addr), so
// pass 2 transposes from xs. 32 KB/block -> 5 blocks/CU.
// ---------------------------------------------------------------------------
__global__ __launch_bounds__(256) void film_mfma_kernel(
    const float* __restrict__ x, const short* __restrict__ nbbf,
    const short* __restrict__ wbf, const float* __restrict__ rvec,
    const float* __restrict__ bias, const float* __restrict__ dinv,
    float* __restrict__ outp, short* __restrict__ xws, short* __restrict__ hsbf) {
    __shared__ short xs[64 * NF];
    __shared__ short ns[64 * NF];

    const short* g1w  = wbf;
    const short* g2w  = wbf + 16384;
    const short* b1w  = wbf + 2 * 16384;
    const short* b2w  = wbf + 3 * 16384;
    const short* linw = wbf + 4 * 16384;

    int tid = threadIdx.x;
    int node0 = blockIdx.x * 64;

    #pragma unroll
    for (int it = 0; it < 4; ++it) {
        int chunk = it * 256 + tid;          // 0..1023
        int row = chunk >> 4;
        int c = chunk & 15;
        int grow = min(node0 + row, NN - 1);
        int swz = ((c ^ (row & 7)) << 3);
        float4 f0 = *(const float4*)(x + grow * NF + c * 8);
        float4 f1 = *(const float4*)(x + grow * NF + c * 8 + 4);
        bf16x8 v;
        v[0] = f2bf(f0.x); v[1] = f2bf(f0.y); v[2] = f2bf(f0.z); v[3] = f2bf(f0.w);
        v[4] = f2bf(f1.x); v[5] = f2bf(f1.y); v[6] = f2bf(f1.z); v[7] = f2bf(f1.w);
        *(bf16x8*)(xs + row * NF + swz) = v;
        *(bf16x8*)(ns + row * NF + swz) = *(const bf16x8*)(nbbf + grow * NF + c * 8);
    }
    __syncthreads();

    int w = tid >> 6;
    int l = tid & 63;
    int lr = l & 15;
    int lg = l >> 4;
    int rowbase = w * 16;

    bf16x8 xf[4], nf[4];
    #pragma unroll
    for (int kb = 0; kb < 4; ++kb) {
        int row = rowbase + lr;
        int swz = (((kb * 4 + lg) ^ (row & 7)) << 3);
        xf[kb] = *(const bf16x8*)(xs + row * NF + swz);
        nf[kb] = *(const bf16x8*)(ns + row * NF + swz);
    }

    float dv[4];
    #pragma unroll
    for (int q = 0; q < 4; ++q)
        dv[q] = dinv[min(node0 + rowbase + lg * 4 + q, NN - 1)];

    // ---- pass 1: FiLM + xw, epilogue writes output back into xs ----
    #pragma unroll 1
    for (int n0 = 0; n0 < 8; ++n0) {
        f32x4 ag = {0.f, 0.f, 0.f, 0.f};
        f32x4 ab = {0.f, 0.f, 0.f, 0.f};
        f32x4 aw = {0.f, 0.f, 0.f, 0.f};
        int wrow = (n0 * 16 + lr) * NF;
        #pragma unroll
        for (int kb = 0; kb < 4; ++kb) {
            int ko = kb * 32 + lg * 8;
            bf16x8 f1 = *(const bf16x8*)(g1w + wrow + ko);
            bf16x8 f2 = *(const bf16x8*)(g2w + wrow + ko);
            bf16x8 f3 = *(const bf16x8*)(b1w + wrow + ko);
            bf16x8 f4 = *(const bf16x8*)(b2w + wrow + ko);
            bf16x8 f5 = *(const bf16x8*)(linw + wrow + ko);
            ag = __builtin_amdgcn_mfma_f32_16x16x32_bf16(xf[kb], f1, ag, 0, 0, 0);
            ag = __builtin_amdgcn_mfma_f32_16x16x32_bf16(nf[kb], f2, ag, 0, 0, 0);
            ab = __builtin_amdgcn_mfma_f32_16x16x32_bf16(xf[kb], f3, ab, 0, 0, 0);
            ab = __builtin_amdgcn_mfma_f32_16x16x32_bf16(nf[kb], f4, ab, 0, 0, 0);
            aw = __builtin_amdgcn_mfma_f32_16x16x32_bf16(xf[kb], f5, aw, 0, 0, 0);
        }
        int col = n0 * 16 + lr;
        float rcol = rvec[col];
        #pragma unroll
        for (int q = 0; q < 4; ++q) {
            int nl = rowbase + lg * 4 + q;
            int ng = node0 + nl;
            int addr = nl * NF + (((col >> 3) ^ (nl & 7)) << 3) + (col & 7);
            float xv = bf2f(xs[addr]);
            float nv = bf2f(ns[addr]);
            float gp = ag[q], bp = ab[q];
            float gamma = (gp >= 0.f ? gp : 0.2f * gp) + 1.0f;
            float beta  = (bp >= 0.f ? bp : 0.2f * bp);
            float o = xv + gamma * rcol + beta - nv;
            xs[addr] = f2bf(o);           // output replaces x in LDS
            if (ng < NN) {
                outp[ng * NF + col] = o;
                xws[ng * NF + col]  = f2bf(dv[q] * aw[q]);
            }
        }
    }
    __syncthreads();

    // ---- pass 2: hsb = output @ lin^T + bias ----
    bf16x8 of[4];
    #pragma unroll
    for (int kb = 0; kb < 4; ++kb) {
        int row = rowbase + lr;
        int swz = (((kb * 4 + lg) ^ (row & 7)) << 3);
        of[kb] = *(const bf16x8*)(xs + row * NF + swz);
    }
    #pragma unroll 1
    for (int n0 = 0; n0 < 8; ++n0) {
        f32x4 as = {0.f, 0.f, 0.f, 0.f};
        int wrow = (n0 * 16 + lr) * NF;
        #pragma unroll
        for (int kb = 0; kb < 4; ++kb) {
            bf16x8 f5 = *(const bf16x8*)(linw + wrow + kb * 32 + lg * 8);
            as = __builtin_amdgcn_mfma_f32_16x16x32_bf16(of[kb], f5, as, 0, 0, 0);
        }
        int col = n0 * 16 + lr;
        float bcol = bias[col];
        #pragma unroll
        for (int q = 0; q < 4; ++q) {
            int ng = node0 + rowbase + lg * 4 + q;
            if (ng < NN) hsbf[ng * NF + col] = f2bf(as[q] + bcol);
        }
    }
}

// ---------------------------------------------------------------------------
// K8: GCN gather + final combine (unroll-2)
// ---------------------------------------------------------------------------
__global__ __launch_bounds__(256) void gather_gcn_kernel(
    const int* __restrict__ offs_c, const int* __restrict__ csr_c,
    const short* __restrict__ xws, const float* __restrict__ dinv,
    const short* __restrict__ hsbf, const int* __restrict__ degr,
    float* __restrict__ hko) {
    int g = blockIdx.x * 16 + (threadIdx.x >> 4);
    int l = threadIdx.x & 15;
    if (g >= NN) return;
    int s = offs_c[g], e = offs_c[g + 1];
    float acc[8];
    bf16x8 self = *(const bf16x8*)(xws + g * NF + l * 8);
    #pragma unroll
    for (int k = 0; k < 8; ++k) acc[k] = bf2f(self[k]);
    int j = s;
    for (; j + 2 <= e; j += 2) {
        int s0 = csr_c[j], s1 = csr_c[j + 1];
        bf16x8 v0 = *(const bf16x8*)(xws + s0 * NF + l * 8);
        bf16x8 v1 = *(const bf16x8*)(xws + s1 * NF + l * 8);
        #pragma unroll
        for (int k = 0; k < 8; ++k) acc[k] += bf2f(v0[k]) + bf2f(v1[k]);
    }
    if (j < e) {
        bf16x8 v = *(const bf16x8*)(xws + csr_c[j] * NF + l * 8);
        #pragma unroll
        for (int k = 0; k < 8; ++k) acc[k] += bf2f(v[k]);
    }
    float dc = dinv[g];
    float invd = 1.0f / ((float)degr[g] + 1.0f);
    bf16x8 h = *(const bf16x8*)(hsbf + g * NF + l * 8);
    float4 o0, o1;
    o0.x = (dc * acc[0] + bf2f(h[0])) * invd;
    o0.y = (dc * acc[1] + bf2f(h[1])) * invd;
    o0.z = (dc * acc[2] + bf2f(h[2])) * invd;
    o0.w = (dc * acc[3] + bf2f(h[3])) * invd;
    o1.x = (dc * acc[4] + bf2f(h[4])) * invd;
    o1.y = (dc * acc[5] + bf2f(h[5])) * invd;
    o1.z = (dc * acc[6] + bf2f(h[6])) * invd;
    o1.w = (dc * acc[7] + bf2f(h[7])) * invd;
    *(float4*)(hko + g * NF + l * 8) = o0;
    *(float4*)(hko + g * NF + l * 8 + 4) = o1;
}

// ---------------------------------------------------------------------------
extern "C" void kernel_launch(void* const* d_in, const int* in_sizes, int n_in,
                              void* d_out, int out_size, void* d_ws, size_t ws_size,
                              hipStream_t stream) {
    const float* x    = (const float*)d_in[0];
    const int*   ei   = (const int*)d_in[1];
    const float* g1   = (const float*)d_in[3];
    const float* g2   = (const float*)d_in[4];
    const float* b1   = (const float*)d_in[5];
    const float* b2   = (const float*)d_in[6];
    const float* rv   = (const float*)d_in[7];
    const float* lin  = (const float*)d_in[8];
    const float* bias = (const float*)d_in[9];

    float* dinv = (float*)d_ws;                  // N
    int* degr   = (int*)(dinv + NN);             // N
    int* offs_r = degr + NN;                     // N+1
    int* offs_c = offs_r + (NN + 1);             // N+1
    int* csr_r  = offs_c + (NN + 1);             // E
    int* csr_c  = csr_r + NE;                    // E
    unsigned* partR = (unsigned*)(csr_c + NE);   // E
    unsigned* partC = partR + NE;                // E
    int* gcnt   = (int*)(partC + NE);            // 2*NB (zeroed)
    int* gcur   = gcnt + 2 * NB;                 // 2*NB
    int* baseR  = gcur + 2 * NB;                 // NB+1
    int* baseC  = baseR + (NB + 1);              // NB+1
    uintptr_t p = (uintptr_t)(baseC + NB + 1);
    p = (p + 15) & ~(uintptr_t)15;
    short* xbf  = (short*)p;                     // N*F bf16
    short* nbbf = xbf + NN * NF;                 // N*F bf16
    short* xws  = nbbf + NN * NF;                // N*F bf16
    short* hsbf = xws + NN * NF;                 // N*F bf16
    short* wbf  = hsbf + NN * NF;                // 5*128*128 bf16

    float* hko  = (float*)d_out;                 // N*F (h_k)
    float* outp = hko + NN * NF;                 // N*F (output)

    hipMemsetAsync(gcnt, 0, 2 * NB * sizeof(int), stream);

    p0_count_kernel<<<PBLOCKS, 256, 0, stream>>>(ei, gcnt);
    p1_scan_kernel<<<1, 256, 0, stream>>>(gcnt, baseR, baseC, gcur);
    p2_partition_kernel<<<PBLOCKS, 256, 0, stream>>>(ei, gcur, partR, partC);
    p3_build_kernel<<<2 * NB, 256, 0, stream>>>(partR, partC, baseR, baseC,
                                                offs_r, offs_c, csr_r, csr_c, degr, dinv);
    convert_x_kernel<<<(NN * NF / 8 + 255) / 256, 256, 0, stream>>>(x, xbf);
    convert_w_kernel<<<(5 * NF * NF + 255) / 256, 256, 0, stream>>>(g1, g2, b1, b2, lin, wbf);
    gather_x_kernel<<<(NN + 15) / 16, 256, 0, stream>>>(offs_r, csr_r, xbf, nbbf);
    film_mfma_kernel<<<(NN + 63) / 64, 256, 0, stream>>>(x, nbbf, wbf, rv, bias, dinv,
                                                         outp, xws, hsbf);
    gather_gcn_kernel<<<(NN + 15) / 16, 256, 0, stream>>>(offs_c, csr_c, xws, dinv,
                                                          hsbf, degr, hko);
}

// Round 6
// 181.883 us; speedup vs baseline: 17.3288x; 1.3554x over previous
//
#include <hip/hip_runtime.h>

#define NN 50000
#define NE 800000
#define NF 128

#define SHIFT 8
#define NB 196            // ceil(50000/256)
#define PBLOCKS 128
#define PCHUNK ((NE + PBLOCKS - 1) / PBLOCKS)   // 6250

#define NTILES ((NN + 63) / 64)   // 782
#define FBLOCKS 512

typedef __attribute__((ext_vector_type(4))) float f32x4;
typedef __attribute__((ext_vector_type(8))) short bf16x8;

__device__ __forceinline__ short f2bf(float f) {
    unsigned u = __float_as_uint(f);
    u += 0x7FFF + ((u >> 16) & 1);      // round-to-nearest-even
    return (short)(u >> 16);
}
__device__ __forceinline__ float bf2f(short s) {
    return __uint_as_float(((unsigned)(unsigned short)s) << 16);
}

// ---------------------------------------------------------------------------
// P0: count edges per coarse bucket (row side and col side) via LDS counters
// ---------------------------------------------------------------------------
__global__ __launch_bounds__(256) void p0_count_kernel(const int* __restrict__ ei,
                                                       int* __restrict__ gcnt) {
    __shared__ int cnt[2 * NB];
    int t = threadIdx.x;
    for (int i = t; i < 2 * NB; i += 256) cnt[i] = 0;
    __syncthreads();
    int lo = blockIdx.x * PCHUNK;
    int hi = min(lo + PCHUNK, NE);
    for (int j = lo + t; j < hi; j += 256) {
        int r = ei[j];
        int c = ei[NE + j];
        atomicAdd(&cnt[r >> SHIFT], 1);
        atomicAdd(&cnt[NB + (c >> SHIFT)], 1);
    }
    __syncthreads();
    for (int i = t; i < 2 * NB; i += 256)
        if (cnt[i]) atomicAdd(&gcnt[i], cnt[i]);
}

// ---------------------------------------------------------------------------
// P1: scan bucket counts -> bases + cursors (one block)
// ---------------------------------------------------------------------------
__global__ __launch_bounds__(256) void p1_scan_kernel(const int* __restrict__ gcnt,
                                                      int* __restrict__ baseR,
                                                      int* __restrict__ baseC,
                                                      int* __restrict__ gcur) {
    __shared__ int s[256];
    int t = threadIdx.x;
    int v = (t < NB) ? gcnt[t] : 0;
    s[t] = v;
    __syncthreads();
    for (int off = 1; off < 256; off <<= 1) {
        int u = (t >= off) ? s[t - off] : 0;
        __syncthreads();
        s[t] += u;
        __syncthreads();
    }
    if (t < NB) {
        int excl = s[t] - v;
        baseR[t] = excl;
        gcur[t] = excl;
        if (t == NB - 1) baseR[NB] = s[t];
    }
    __syncthreads();
    int v2 = (t < NB) ? gcnt[NB + t] : 0;
    s[t] = v2;
    __syncthreads();
    for (int off = 1; off < 256; off <<= 1) {
        int u = (t >= off) ? s[t - off] : 0;
        __syncthreads();
        s[t] += u;
        __syncthreads();
    }
    if (t < NB) {
        int excl = s[t] - v2;
        baseC[t] = excl;
        gcur[NB + t] = excl;
        if (t == NB - 1) baseC[NB] = s[t];
    }
}

// ---------------------------------------------------------------------------
// P2: partition edges into bucket-contiguous arrays, 4B packed entries:
//     entry = (local_key << 17) | payload
// ---------------------------------------------------------------------------
__global__ __launch_bounds__(256) void p2_partition_kernel(const int* __restrict__ ei,
                                                           int* __restrict__ gcur,
                                                           unsigned* __restrict__ partR,
                                                           unsigned* __restrict__ partC) {
    __shared__ int cnt[2 * NB];
    __shared__ int res[2 * NB];
    int t = threadIdx.x;
    for (int i = t; i < 2 * NB; i += 256) cnt[i] = 0;
    __syncthreads();
    int lo = blockIdx.x * PCHUNK;
    int hi = min(lo + PCHUNK, NE);
    for (int j = lo + t; j < hi; j += 256) {
        int r = ei[j];
        int c = ei[NE + j];
        atomicAdd(&cnt[r >> SHIFT], 1);
        atomicAdd(&cnt[NB + (c >> SHIFT)], 1);
    }
    __syncthreads();
    for (int i = t; i < 2 * NB; i += 256) {
        int n = cnt[i];
        res[i] = n ? atomicAdd(&gcur[i], n) : 0;
        cnt[i] = 0;
    }
    __syncthreads();
    for (int j = lo + t; j < hi; j += 256) {
        int r = ei[j];
        int c = ei[NE + j];
        int bR = r >> SHIFT;
        int sR = atomicAdd(&cnt[bR], 1);
        partR[res[bR] + sR] = ((unsigned)(r & 255) << 17) | (unsigned)c;
        int bC = NB + (c >> SHIFT);
        int sC = atomicAdd(&cnt[bC], 1);
        partC[res[bC] + sC] = ((unsigned)(c & 255) << 17) | (unsigned)r;
    }
}

// ---------------------------------------------------------------------------
// P3: per (side,bucket): degree count -> scan -> offs/deg/dinv -> place CSR
// ---------------------------------------------------------------------------
__global__ __launch_bounds__(256) void p3_build_kernel(
    const unsigned* __restrict__ partR, const unsigned* __restrict__ partC,
    const int* __restrict__ baseR, const int* __restrict__ baseC,
    int* __restrict__ offs_r, int* __restrict__ offs_c,
    int* __restrict__ csr_r, int* __restrict__ csr_c,
    int* __restrict__ degr, float* __restrict__ dinv) {
    int side = blockIdx.x / NB;
    int b = blockIdx.x - side * NB;
    const unsigned* part = side ? partC : partR;
    const int* base = side ? baseC : baseR;
    int* offs = side ? offs_c : offs_r;
    int* csr = side ? csr_c : csr_r;

    __shared__ int deg[256];
    __shared__ int cur[256];
    int t = threadIdx.x;
    int s0 = base[b], s1 = base[b + 1];
    deg[t] = 0;
    __syncthreads();
    for (int j = s0 + t; j < s1; j += 256)
        atomicAdd(&deg[part[j] >> 17], 1);
    __syncthreads();
    int myDeg = deg[t];
    for (int off = 1; off < 256; off <<= 1) {
        int u = (t >= off) ? deg[t - off] : 0;
        __syncthreads();
        deg[t] += u;
        __syncthreads();
    }
    int excl = deg[t] - myDeg;
    int node = (b << SHIFT) + t;
    if (node <= NN) offs[node] = s0 + excl;
    if (node < NN) {
        if (side == 0) degr[node] = myDeg;
        else           dinv[node] = rsqrtf((float)myDeg + 1.0f);
    }
    cur[t] = excl;
    __syncthreads();
    for (int j = s0 + t; j < s1; j += 256) {
        unsigned en = part[j];
        int k = en >> 17;
        int p = atomicAdd(&cur[k], 1);
        csr[s0 + p] = (int)(en & 0x1FFFFu);
    }
}

// ---------------------------------------------------------------------------
// K5a: x f32 -> bf16
// ---------------------------------------------------------------------------
__global__ void convert_x_kernel(const float* __restrict__ x, short* __restrict__ xbf) {
    int i = blockIdx.x * blockDim.x + threadIdx.x;
    if (i >= NN * NF / 8) return;
    float4 a = ((const float4*)x)[i * 2];
    float4 b = ((const float4*)x)[i * 2 + 1];
    bf16x8 v;
    v[0] = f2bf(a.x); v[1] = f2bf(a.y); v[2] = f2bf(a.z); v[3] = f2bf(a.w);
    v[4] = f2bf(b.x); v[5] = f2bf(b.y); v[6] = f2bf(b.z); v[7] = f2bf(b.w);
    *(bf16x8*)(xbf + i * 8) = v;
}

// ---------------------------------------------------------------------------
// K5b: 5 weight matrices f32 -> bf16 (stacked [5][128][128])
// ---------------------------------------------------------------------------
__global__ void convert_w_kernel(const float* __restrict__ g1, const float* __restrict__ g2,
                                 const float* __restrict__ b1, const float* __restrict__ b2,
                                 const float* __restrict__ lin, short* __restrict__ wbf) {
    int i = blockIdx.x * blockDim.x + threadIdx.x;
    if (i >= 5 * NF * NF) return;
    int m = i >> 14, off = i & (NF * NF - 1);
    float v = (m == 0) ? g1[off] : (m == 1) ? g2[off] : (m == 2) ? b1[off]
            : (m == 3) ? b2[off] : lin[off];
    wbf[i] = f2bf(v);
}

// ---------------------------------------------------------------------------
// K6: neighbor mean gather (bf16 payload), unroll-2 for MLP.
// ---------------------------------------------------------------------------
__global__ __launch_bounds__(256) void gather_x_kernel(
    const int* __restrict__ offs_r, const int* __restrict__ csr_r,
    const short* __restrict__ xbf, short* __restrict__ nbbf) {
    int g = blockIdx.x * 16 + (threadIdx.x >> 4);
    int l = threadIdx.x & 15;
    if (g >= NN) return;
    int s = offs_r[g], e = offs_r[g + 1];
    float acc[8] = {0.f, 0.f, 0.f, 0.f, 0.f, 0.f, 0.f, 0.f};
    int j = s;
    for (; j + 2 <= e; j += 2) {
        int s0 = csr_r[j], s1 = csr_r[j + 1];
        bf16x8 v0 = *(const bf16x8*)(xbf + s0 * NF + l * 8);
        bf16x8 v1 = *(const bf16x8*)(xbf + s1 * NF + l * 8);
        #pragma unroll
        for (int k = 0; k < 8; ++k) acc[k] += bf2f(v0[k]) + bf2f(v1[k]);
    }
    if (j < e) {
        bf16x8 v = *(const bf16x8*)(xbf + csr_r[j] * NF + l * 8);
        #pragma unroll
        for (int k = 0; k < 8; ++k) acc[k] += bf2f(v[k]);
    }
    float inv = 1.0f / fmaxf((float)(e - s), 1.0f);
    bf16x8 o;
    #pragma unroll
    for (int k = 0; k < 8; ++k) o[k] = f2bf(acc[k] * inv);
    *(bf16x8*)(nbbf + g * NF + l * 8) = o;
}

// ---------------------------------------------------------------------------
// K7: fused FiLM (5 GEMMs) + h_s GEMM, MFMA 16x16x32 bf16.
// REGISTER-RESIDENT WEIGHTS: wave w owns output cols [w*32, w*32+32) (2 n0
// tiles); its 40 weight fragments (160 VGPRs) are loaded ONCE per block and
// every MFMA issues from registers. Waves loop over 4 row-groups of the
// 64-node LDS tile, then grid-stride to the next tile (weights reused).
// LDS: xs + ns + os = 48 KB. 2 barriers per tile.
// ---------------------------------------------------------------------------
__global__ __launch_bounds__(256, 2) void film_mfma_kernel(
    const float* __restrict__ x, const short* __restrict__ nbbf,
    const short* __restrict__ wbf, const float* __restrict__ rvec,
    const float* __restrict__ bias, const float* __restrict__ dinv,
    float* __restrict__ outp, short* __restrict__ xws, short* __restrict__ hsbf) {
    __shared__ short xs[64 * NF];
    __shared__ short ns[64 * NF];
    __shared__ short os[64 * NF];

    int tid = threadIdx.x;
    int w = tid >> 6;
    int l = tid & 63;
    int lr = l & 15;
    int lg = l >> 4;

    // ---- one-time: weight fragments into registers ----
    // wf[j][m][kb]: B-frag for out-cols (2w+j)*16+lr, matrix m, k-block kb
    bf16x8 wf[2][5][4];
    float rc[2], bc[2];
    #pragma unroll
    for (int j = 0; j < 2; ++j) {
        int col = (2 * w + j) * 16 + lr;
        #pragma unroll
        for (int m = 0; m < 5; ++m) {
            const short* wm = wbf + m * 16384 + col * NF;
            #pragma unroll
            for (int kb = 0; kb < 4; ++kb)
                wf[j][m][kb] = *(const bf16x8*)(wm + kb * 32 + lg * 8);
        }
        rc[j] = rvec[col];
        bc[j] = bias[col];
    }

    #pragma unroll 1
    for (int tile = blockIdx.x; tile < NTILES; tile += FBLOCKS) {
        int node0 = tile * 64;

        // ---- stage x (f32->bf16) and nb into swizzled LDS ----
        #pragma unroll
        for (int it = 0; it < 4; ++it) {
            int chunk = it * 256 + tid;          // 0..1023
            int row = chunk >> 4;
            int c = chunk & 15;
            int grow = min(node0 + row, NN - 1);
            int swz = ((c ^ (row & 7)) << 3);
            float4 f0 = *(const float4*)(x + grow * NF + c * 8);
            float4 f1 = *(const float4*)(x + grow * NF + c * 8 + 4);
            bf16x8 v;
            v[0] = f2bf(f0.x); v[1] = f2bf(f0.y); v[2] = f2bf(f0.z); v[3] = f2bf(f0.w);
            v[4] = f2bf(f1.x); v[5] = f2bf(f1.y); v[6] = f2bf(f1.z); v[7] = f2bf(f1.w);
            *(bf16x8*)(xs + row * NF + swz) = v;
            *(bf16x8*)(ns + row * NF + swz) = *(const bf16x8*)(nbbf + grow * NF + c * 8);
        }
        __syncthreads();

        // ---- pass 1: FiLM + xw over 4 row-groups ----
        #pragma unroll 1
        for (int rg = 0; rg < 4; ++rg) {
            bf16x8 xf[4], nf[4];
            #pragma unroll
            for (int kb = 0; kb < 4; ++kb) {
                int row = rg * 16 + lr;
                int swz = (((kb * 4 + lg) ^ (row & 7)) << 3);
                xf[kb] = *(const bf16x8*)(xs + row * NF + swz);
                nf[kb] = *(const bf16x8*)(ns + row * NF + swz);
            }
            float dvq[4];
            #pragma unroll
            for (int q = 0; q < 4; ++q)
                dvq[q] = dinv[min(node0 + rg * 16 + lg * 4 + q, NN - 1)];

            #pragma unroll
            for (int j = 0; j < 2; ++j) {
                f32x4 ag = {0.f, 0.f, 0.f, 0.f};
                f32x4 ab = {0.f, 0.f, 0.f, 0.f};
                f32x4 aw = {0.f, 0.f, 0.f, 0.f};
                #pragma unroll
                for (int kb = 0; kb < 4; ++kb) {
                    ag = __builtin_amdgcn_mfma_f32_16x16x32_bf16(xf[kb], wf[j][0][kb], ag, 0, 0, 0);
                    ag = __builtin_amdgcn_mfma_f32_16x16x32_bf16(nf[kb], wf[j][1][kb], ag, 0, 0, 0);
                    ab = __builtin_amdgcn_mfma_f32_16x16x32_bf16(xf[kb], wf[j][2][kb], ab, 0, 0, 0);
                    ab = __builtin_amdgcn_mfma_f32_16x16x32_bf16(nf[kb], wf[j][3][kb], ab, 0, 0, 0);
                    aw = __builtin_amdgcn_mfma_f32_16x16x32_bf16(xf[kb], wf[j][4][kb], aw, 0, 0, 0);
                }
                int col = (2 * w + j) * 16 + lr;
                #pragma unroll
                for (int q = 0; q < 4; ++q) {
                    int nl = rg * 16 + lg * 4 + q;
                    int ng = node0 + nl;
                    int addr = nl * NF + (((col >> 3) ^ (nl & 7)) << 3) + (col & 7);
                    float xv = bf2f(xs[addr]);
                    float nv = bf2f(ns[addr]);
                    float gp = ag[q], bp = ab[q];
                    float gamma = (gp >= 0.f ? gp : 0.2f * gp) + 1.0f;
                    float beta  = (bp >= 0.f ? bp : 0.2f * bp);
                    float o = xv + gamma * rc[j] + beta - nv;
                    os[addr] = f2bf(o);
                    if (ng < NN) {
                        outp[ng * NF + col] = o;
                        xws[ng * NF + col]  = f2bf(dvq[q] * aw[q]);
                    }
                }
            }
        }
        __syncthreads();

        // ---- pass 2: hsb = output @ lin^T + bias ----
        #pragma unroll 1
        for (int rg = 0; rg < 4; ++rg) {
            bf16x8 of[4];
            #pragma unroll
            for (int kb = 0; kb < 4; ++kb) {
                int row = rg * 16 + lr;
                int swz = (((kb * 4 + lg) ^ (row & 7)) << 3);
                of[kb] = *(const bf16x8*)(os + row * NF + swz);
            }
            #pragma unroll
            for (int j = 0; j < 2; ++j) {
                f32x4 as = {0.f, 0.f, 0.f, 0.f};
                #pragma unroll
                for (int kb = 0; kb < 4; ++kb)
                    as = __builtin_amdgcn_mfma_f32_16x16x32_bf16(of[kb], wf[j][4][kb], as, 0, 0, 0);
                int col = (2 * w + j) * 16 + lr;
                #pragma unroll
                for (int q = 0; q < 4; ++q) {
                    int ng = node0 + rg * 16 + lg * 4 + q;
                    if (ng < NN) hsbf[ng * NF + col] = f2bf(as[q] + bc[j]);
                }
            }
        }
        // no barrier needed: next stage writes xs/ns, pass 2 reads only os
    }
}

// ---------------------------------------------------------------------------
// K8: GCN gather + final combine (unroll-2)
// ---------------------------------------------------------------------------
__global__ __launch_bounds__(256) void gather_gcn_kernel(
    const int* __restrict__ offs_c, const int* __restrict__ csr_c,
    const short* __restrict__ xws, const float* __restrict__ dinv,
    const short* __restrict__ hsbf, const int* __restrict__ degr,
    float* __restrict__ hko) {
    int g = blockIdx.x * 16 + (threadIdx.x >> 4);
    int l = threadIdx.x & 15;
    if (g >= NN) return;
    int s = offs_c[g], e = offs_c[g + 1];
    float acc[8];
    bf16x8 self = *(const bf16x8*)(xws + g * NF + l * 8);
    #pragma unroll
    for (int k = 0; k < 8; ++k) acc[k] = bf2f(self[k]);
    int j = s;
    for (; j + 2 <= e; j += 2) {
        int s0 = csr_c[j], s1 = csr_c[j + 1];
        bf16x8 v0 = *(const bf16x8*)(xws + s0 * NF + l * 8);
        bf16x8 v1 = *(const bf16x8*)(xws + s1 * NF + l * 8);
        #pragma unroll
        for (int k = 0; k < 8; ++k) acc[k] += bf2f(v0[k]) + bf2f(v1[k]);
    }
    if (j < e) {
        bf16x8 v = *(const bf16x8*)(xws + csr_c[j] * NF + l * 8);
        #pragma unroll
        for (int k = 0; k < 8; ++k) acc[k] += bf2f(v[k]);
    }
    float dc = dinv[g];
    float invd = 1.0f / ((float)degr[g] + 1.0f);
    bf16x8 h = *(const bf16x8*)(hsbf + g * NF + l * 8);
    float4 o0, o1;
    o0.x = (dc * acc[0] + bf2f(h[0])) * invd;
    o0.y = (dc * acc[1] + bf2f(h[1])) * invd;
    o0.z = (dc * acc[2] + bf2f(h[2])) * invd;
    o0.w = (dc * acc[3] + bf2f(h[3])) * invd;
    o1.x = (dc * acc[4] + bf2f(h[4])) * invd;
    o1.y = (dc * acc[5] + bf2f(h[5])) * invd;
    o1.z = (dc * acc[6] + bf2f(h[6])) * invd;
    o1.w = (dc * acc[7] + bf2f(h[7])) * invd;
    *(float4*)(hko + g * NF + l * 8) = o0;
    *(float4*)(hko + g * NF + l * 8 + 4) = o1;
}

// ---------------------------------------------------------------------------
extern "C" void kernel_launch(void* const* d_in, const int* in_sizes, int n_in,
                              void* d_out, int out_size, void* d_ws, size_t ws_size,
                              hipStream_t stream) {
    const float* x    = (const float*)d_in[0];
    const int*   ei   = (const int*)d_in[1];
    const float* g1   = (const float*)d_in[3];
    const float* g2   = (const float*)d_in[4];
    const float* b1   = (const float*)d_in[5];
    const float* b2   = (const float*)d_in[6];
    const float* rv   = (const float*)d_in[7];
    const float* lin  = (const float*)d_in[8];
    const float* bias = (const float*)d_in[9];

    float* dinv = (float*)d_ws;                  // N
    int* degr   = (int*)(dinv + NN);             // N
    int* offs_r = degr + NN;                     // N+1
    int* offs_c = offs_r + (NN + 1);             // N+1
    int* csr_r  = offs_c + (NN + 1);             // E
    int* csr_c  = csr_r + NE;                    // E
    unsigned* partR = (unsigned*)(csr_c + NE);   // E
    unsigned* partC = partR + NE;                // E
    int* gcnt   = (int*)(partC + NE);            // 2*NB (zeroed)
    int* gcur   = gcnt + 2 * NB;                 // 2*NB
    int* baseR  = gcur + 2 * NB;                 // NB+1
    int* baseC  = baseR + (NB + 1);              // NB+1
    uintptr_t p = (uintptr_t)(baseC + NB + 1);
    p = (p + 15) & ~(uintptr_t)15;
    short* xbf  = (short*)p;                     // N*F bf16
    short* nbbf = xbf + NN * NF;                 // N*F bf16
    short* xws  = nbbf + NN * NF;                // N*F bf16
    short* hsbf = xws + NN * NF;                 // N*F bf16
    short* wbf  = hsbf + NN * NF;                // 5*128*128 bf16

    float* hko  = (float*)d_out;                 // N*F (h_k)
    float* outp = hko + NN * NF;                 // N*F (output)

    hipMemsetAsync(gcnt, 0, 2 * NB * sizeof(int), stream);

    p0_count_kernel<<<PBLOCKS, 256, 0, stream>>>(ei, gcnt);
    p1_scan_kernel<<<1, 256, 0, stream>>>(gcnt, baseR, baseC, gcur);
    p2_partition_kernel<<<PBLOCKS, 256, 0, stream>>>(ei, gcur, partR, partC);
    p3_build_kernel<<<2 * NB, 256, 0, stream>>>(partR, partC, baseR, baseC,
                                                offs_r, offs_c, csr_r, csr_c, degr, dinv);
    convert_x_kernel<<<(NN * NF / 8 + 255) / 256, 256, 0, stream>>>(x, xbf);
    convert_w_kernel<<<(5 * NF * NF + 255) / 256, 256, 0, stream>>>(g1, g2, b1, b2, lin, wbf);
    gather_x_kernel<<<(NN + 15) / 16, 256, 0, stream>>>(offs_r, csr_r, xbf, nbbf);
    film_mfma_kernel<<<FBLOCKS, 256, 0, stream>>>(x, nbbf, wbf, rv, bias, dinv,
                                                  outp, xws, hsbf);
    gather_gcn_kernel<<<(NN + 15) / 16, 256, 0, stream>>>(offs_c, csr_c, xws, dinv,
                                                          hsbf, degr, hko);
}

// Round 7
// 175.229 us; speedup vs baseline: 17.9869x; 1.0380x over previous
//
#include <hip/hip_runtime.h>

#define NN 50000
#define NE 800000
#define NF 128

#define SHIFT 8
#define NB 196            // ceil(50000/256)
#define PBLOCKS 128
#define PCHUNK ((NE + PBLOCKS - 1) / PBLOCKS)   // 6250

#define NTILES ((NN + 63) / 64)   // 782
#define FBLOCKS 512

typedef __attribute__((ext_vector_type(4))) float f32x4;
typedef __attribute__((ext_vector_type(8))) short bf16x8;

__device__ __forceinline__ short f2bf(float f) {
    unsigned u = __float_as_uint(f);
    u += 0x7FFF + ((u >> 16) & 1);      // round-to-nearest-even
    return (short)(u >> 16);
}
__device__ __forceinline__ float bf2f(short s) {
    return __uint_as_float(((unsigned)(unsigned short)s) << 16);
}

// ---------------------------------------------------------------------------
// P0: count edges per coarse bucket (row side and col side) via LDS counters
// ---------------------------------------------------------------------------
__global__ __launch_bounds__(256) void p0_count_kernel(const int* __restrict__ ei,
                                                       int* __restrict__ gcnt) {
    __shared__ int cnt[2 * NB];
    int t = threadIdx.x;
    for (int i = t; i < 2 * NB; i += 256) cnt[i] = 0;
    __syncthreads();
    int lo = blockIdx.x * PCHUNK;
    int hi = min(lo + PCHUNK, NE);
    for (int j = lo + t; j < hi; j += 256) {
        int r = ei[j];
        int c = ei[NE + j];
        atomicAdd(&cnt[r >> SHIFT], 1);
        atomicAdd(&cnt[NB + (c >> SHIFT)], 1);
    }
    __syncthreads();
    for (int i = t; i < 2 * NB; i += 256)
        if (cnt[i]) atomicAdd(&gcnt[i], cnt[i]);
}

// ---------------------------------------------------------------------------
// P1: scan bucket counts -> bases + cursors (one block)
// ---------------------------------------------------------------------------
__global__ __launch_bounds__(256) void p1_scan_kernel(const int* __restrict__ gcnt,
                                                      int* __restrict__ baseR,
                                                      int* __restrict__ baseC,
                                                      int* __restrict__ gcur) {
    __shared__ int s[256];
    int t = threadIdx.x;
    int v = (t < NB) ? gcnt[t] : 0;
    s[t] = v;
    __syncthreads();
    for (int off = 1; off < 256; off <<= 1) {
        int u = (t >= off) ? s[t - off] : 0;
        __syncthreads();
        s[t] += u;
        __syncthreads();
    }
    if (t < NB) {
        int excl = s[t] - v;
        baseR[t] = excl;
        gcur[t] = excl;
        if (t == NB - 1) baseR[NB] = s[t];
    }
    __syncthreads();
    int v2 = (t < NB) ? gcnt[NB + t] : 0;
    s[t] = v2;
    __syncthreads();
    for (int off = 1; off < 256; off <<= 1) {
        int u = (t >= off) ? s[t - off] : 0;
        __syncthreads();
        s[t] += u;
        __syncthreads();
    }
    if (t < NB) {
        int excl = s[t] - v2;
        baseC[t] = excl;
        gcur[NB + t] = excl;
        if (t == NB - 1) baseC[NB] = s[t];
    }
}

// ---------------------------------------------------------------------------
// P2: partition edges into bucket-contiguous arrays, 4B packed entries:
//     entry = (local_key << 17) | payload
// ---------------------------------------------------------------------------
__global__ __launch_bounds__(256) void p2_partition_kernel(const int* __restrict__ ei,
                                                           int* __restrict__ gcur,
                                                           unsigned* __restrict__ partR,
                                                           unsigned* __restrict__ partC) {
    __shared__ int cnt[2 * NB];
    __shared__ int res[2 * NB];
    int t = threadIdx.x;
    for (int i = t; i < 2 * NB; i += 256) cnt[i] = 0;
    __syncthreads();
    int lo = blockIdx.x * PCHUNK;
    int hi = min(lo + PCHUNK, NE);
    for (int j = lo + t; j < hi; j += 256) {
        int r = ei[j];
        int c = ei[NE + j];
        atomicAdd(&cnt[r >> SHIFT], 1);
        atomicAdd(&cnt[NB + (c >> SHIFT)], 1);
    }
    __syncthreads();
    for (int i = t; i < 2 * NB; i += 256) {
        int n = cnt[i];
        res[i] = n ? atomicAdd(&gcur[i], n) : 0;
        cnt[i] = 0;
    }
    __syncthreads();
    for (int j = lo + t; j < hi; j += 256) {
        int r = ei[j];
        int c = ei[NE + j];
        int bR = r >> SHIFT;
        int sR = atomicAdd(&cnt[bR], 1);
        partR[res[bR] + sR] = ((unsigned)(r & 255) << 17) | (unsigned)c;
        int bC = NB + (c >> SHIFT);
        int sC = atomicAdd(&cnt[bC], 1);
        partC[res[bC] + sC] = ((unsigned)(c & 255) << 17) | (unsigned)r;
    }
}

// ---------------------------------------------------------------------------
// P3: per (side,bucket): degree count -> scan -> offs/deg/dinv -> place CSR
// ---------------------------------------------------------------------------
__global__ __launch_bounds__(256) void p3_build_kernel(
    const unsigned* __restrict__ partR, const unsigned* __restrict__ partC,
    const int* __restrict__ baseR, const int* __restrict__ baseC,
    int* __restrict__ offs_r, int* __restrict__ offs_c,
    int* __restrict__ csr_r, int* __restrict__ csr_c,
    int* __restrict__ degr, float* __restrict__ dinv) {
    int side = blockIdx.x / NB;
    int b = blockIdx.x - side * NB;
    const unsigned* part = side ? partC : partR;
    const int* base = side ? baseC : baseR;
    int* offs = side ? offs_c : offs_r;
    int* csr = side ? csr_c : csr_r;

    __shared__ int deg[256];
    __shared__ int cur[256];
    int t = threadIdx.x;
    int s0 = base[b], s1 = base[b + 1];
    deg[t] = 0;
    __syncthreads();
    for (int j = s0 + t; j < s1; j += 256)
        atomicAdd(&deg[part[j] >> 17], 1);
    __syncthreads();
    int myDeg = deg[t];
    for (int off = 1; off < 256; off <<= 1) {
        int u = (t >= off) ? deg[t - off] : 0;
        __syncthreads();
        deg[t] += u;
        __syncthreads();
    }
    int excl = deg[t] - myDeg;
    int node = (b << SHIFT) + t;
    if (node <= NN) offs[node] = s0 + excl;
    if (node < NN) {
        if (side == 0) degr[node] = myDeg;
        else           dinv[node] = rsqrtf((float)myDeg + 1.0f);
    }
    cur[t] = excl;
    __syncthreads();
    for (int j = s0 + t; j < s1; j += 256) {
        unsigned en = part[j];
        int k = en >> 17;
        int p = atomicAdd(&cur[k], 1);
        csr[s0 + p] = (int)(en & 0x1FFFFu);
    }
}

// ---------------------------------------------------------------------------
// K5a: x f32 -> bf16
// ---------------------------------------------------------------------------
__global__ void convert_x_kernel(const float* __restrict__ x, short* __restrict__ xbf) {
    int i = blockIdx.x * blockDim.x + threadIdx.x;
    if (i >= NN * NF / 8) return;
    float4 a = ((const float4*)x)[i * 2];
    float4 b = ((const float4*)x)[i * 2 + 1];
    bf16x8 v;
    v[0] = f2bf(a.x); v[1] = f2bf(a.y); v[2] = f2bf(a.z); v[3] = f2bf(a.w);
    v[4] = f2bf(b.x); v[5] = f2bf(b.y); v[6] = f2bf(b.z); v[7] = f2bf(b.w);
    *(bf16x8*)(xbf + i * 8) = v;
}

// ---------------------------------------------------------------------------
// K5b: 5 weight matrices f32 -> bf16 (stacked [5][128][128])
// ---------------------------------------------------------------------------
__global__ void convert_w_kernel(const float* __restrict__ g1, const float* __restrict__ g2,
                                 const float* __restrict__ b1, const float* __restrict__ b2,
                                 const float* __restrict__ lin, short* __restrict__ wbf) {
    int i = blockIdx.x * blockDim.x + threadIdx.x;
    if (i >= 5 * NF * NF) return;
    int m = i >> 14, off = i & (NF * NF - 1);
    float v = (m == 0) ? g1[off] : (m == 1) ? g2[off] : (m == 2) ? b1[off]
            : (m == 3) ? b2[off] : lin[off];
    wbf[i] = f2bf(v);
}

// ---------------------------------------------------------------------------
// K6: FUSED gather: for each node g,
//   nb[g] = mean_{src in csr_r[g]} x[src]
//   z[g]  = dinv[g] * ( sum_{src in csr_c[g]} dinv[src]*x[src] + dinv[g]*x[g] )
// Both loops read the SAME xbf array (12.8 MB L2/L3 working set).
// 16 lanes per node (bf16x8 each), 16 nodes per 256-thread block, unroll-2.
// ---------------------------------------------------------------------------
__global__ __launch_bounds__(256) void gather_fused_kernel(
    const int* __restrict__ offs_r, const int* __restrict__ csr_r,
    const int* __restrict__ offs_c, const int* __restrict__ csr_c,
    const short* __restrict__ xbf, const float* __restrict__ dinv,
    short* __restrict__ nbbf, short* __restrict__ zbf) {
    int g = blockIdx.x * 16 + (threadIdx.x >> 4);
    int l = threadIdx.x & 15;
    if (g >= NN) return;
    const short* xb = xbf + l * 8;

    // ---- row side: neighbor mean ----
    int s = offs_r[g], e = offs_r[g + 1];
    float acc[8] = {0.f, 0.f, 0.f, 0.f, 0.f, 0.f, 0.f, 0.f};
    int j = s;
    for (; j + 2 <= e; j += 2) {
        int s0 = csr_r[j], s1 = csr_r[j + 1];
        bf16x8 v0 = *(const bf16x8*)(xb + s0 * NF);
        bf16x8 v1 = *(const bf16x8*)(xb + s1 * NF);
        #pragma unroll
        for (int k = 0; k < 8; ++k) acc[k] += bf2f(v0[k]) + bf2f(v1[k]);
    }
    if (j < e) {
        bf16x8 v = *(const bf16x8*)(xb + csr_r[j] * NF);
        #pragma unroll
        for (int k = 0; k < 8; ++k) acc[k] += bf2f(v[k]);
    }
    float invn = 1.0f / fmaxf((float)(e - s), 1.0f);
    bf16x8 o;
    #pragma unroll
    for (int k = 0; k < 8; ++k) o[k] = f2bf(acc[k] * invn);
    *(bf16x8*)(nbbf + g * NF + l * 8) = o;

    // ---- col side: z aggregation ----
    s = offs_c[g]; e = offs_c[g + 1];
    float az[8] = {0.f, 0.f, 0.f, 0.f, 0.f, 0.f, 0.f, 0.f};
    j = s;
    for (; j + 2 <= e; j += 2) {
        int s0 = csr_c[j], s1 = csr_c[j + 1];
        float w0 = dinv[s0], w1 = dinv[s1];
        bf16x8 v0 = *(const bf16x8*)(xb + s0 * NF);
        bf16x8 v1 = *(const bf16x8*)(xb + s1 * NF);
        #pragma unroll
        for (int k = 0; k < 8; ++k) az[k] += w0 * bf2f(v0[k]) + w1 * bf2f(v1[k]);
    }
    if (j < e) {
        int s0 = csr_c[j];
        float w0 = dinv[s0];
        bf16x8 v = *(const bf16x8*)(xb + s0 * NF);
        #pragma unroll
        for (int k = 0; k < 8; ++k) az[k] += w0 * bf2f(v[k]);
    }
    float dc = dinv[g];
    bf16x8 self = *(const bf16x8*)(xb + g * NF);
    bf16x8 zo;
    #pragma unroll
    for (int k = 0; k < 8; ++k) zo[k] = f2bf(dc * (az[k] + dc * bf2f(self[k])));
    *(bf16x8*)(zbf + g * NF + l * 8) = zo;
}

// ---------------------------------------------------------------------------
// K7: fused FiLM (4 GEMMs) + final GEMM, MFMA 16x16x32 bf16.
// Register-resident weights (wave w owns cols [w*32,w*32+32), 40 frags).
// Pass 1: ag = x@g1 + nb@g2 ; ab = x@b1 + nb@b2
//         output = x + (lrelu(ag)+1)*r + lrelu(ab) - nb  -> d_out (f32)
//         t = output + z  -> written back into zs LDS (in place)
// Pass 2: h_k = (t @ lin^T + bias) / (deg_r + 1)  -> d_out (f32)
// LDS: xs + ns + zs = 48 KB. Grid-stride over 64-node tiles.
// ---------------------------------------------------------------------------
__global__ __launch_bounds__(256, 2) void film_mfma_kernel(
    const short* __restrict__ xbf, const short* __restrict__ nbbf,
    const short* __restrict__ zbf, const short* __restrict__ wbf,
    const float* __restrict__ rvec, const float* __restrict__ bias,
    const int* __restrict__ degr, float* __restrict__ outp,
    float* __restrict__ hko) {
    __shared__ short xs[64 * NF];
    __shared__ short ns[64 * NF];
    __shared__ short zs[64 * NF];

    int tid = threadIdx.x;
    int w = tid >> 6;
    int l = tid & 63;
    int lr = l & 15;
    int lg = l >> 4;

    // ---- one-time: weight fragments into registers ----
    bf16x8 wf[2][5][4];
    float rc[2], bc[2];
    #pragma unroll
    for (int j = 0; j < 2; ++j) {
        int col = (2 * w + j) * 16 + lr;
        #pragma unroll
        for (int m = 0; m < 5; ++m) {
            const short* wm = wbf + m * 16384 + col * NF;
            #pragma unroll
            for (int kb = 0; kb < 4; ++kb)
                wf[j][m][kb] = *(const bf16x8*)(wm + kb * 32 + lg * 8);
        }
        rc[j] = rvec[col];
        bc[j] = bias[col];
    }

    #pragma unroll 1
    for (int tile = blockIdx.x; tile < NTILES; tile += FBLOCKS) {
        int node0 = tile * 64;

        // ---- stage x, nb, z into swizzled LDS (all bf16) ----
        #pragma unroll
        for (int it = 0; it < 4; ++it) {
            int chunk = it * 256 + tid;          // 0..1023
            int row = chunk >> 4;
            int c = chunk & 15;
            int grow = min(node0 + row, NN - 1);
            int swz = ((c ^ (row & 7)) << 3);
            *(bf16x8*)(xs + row * NF + swz) = *(const bf16x8*)(xbf + grow * NF + c * 8);
            *(bf16x8*)(ns + row * NF + swz) = *(const bf16x8*)(nbbf + grow * NF + c * 8);
            *(bf16x8*)(zs + row * NF + swz) = *(const bf16x8*)(zbf + grow * NF + c * 8);
        }
        __syncthreads();

        // ---- pass 1: FiLM over 4 row-groups ----
        #pragma unroll 1
        for (int rg = 0; rg < 4; ++rg) {
            bf16x8 xf[4], nf[4];
            #pragma unroll
            for (int kb = 0; kb < 4; ++kb) {
                int row = rg * 16 + lr;
                int swz = (((kb * 4 + lg) ^ (row & 7)) << 3);
                xf[kb] = *(const bf16x8*)(xs + row * NF + swz);
                nf[kb] = *(const bf16x8*)(ns + row * NF + swz);
            }
            #pragma unroll
            for (int j = 0; j < 2; ++j) {
                f32x4 ag = {0.f, 0.f, 0.f, 0.f};
                f32x4 ab = {0.f, 0.f, 0.f, 0.f};
                #pragma unroll
                for (int kb = 0; kb < 4; ++kb) {
                    ag = __builtin_amdgcn_mfma_f32_16x16x32_bf16(xf[kb], wf[j][0][kb], ag, 0, 0, 0);
                    ag = __builtin_amdgcn_mfma_f32_16x16x32_bf16(nf[kb], wf[j][1][kb], ag, 0, 0, 0);
                    ab = __builtin_amdgcn_mfma_f32_16x16x32_bf16(xf[kb], wf[j][2][kb], ab, 0, 0, 0);
                    ab = __builtin_amdgcn_mfma_f32_16x16x32_bf16(nf[kb], wf[j][3][kb], ab, 0, 0, 0);
                }
                int col = (2 * w + j) * 16 + lr;
                #pragma unroll
                for (int q = 0; q < 4; ++q) {
                    int nl = rg * 16 + lg * 4 + q;
                    int ng = node0 + nl;
                    int addr = nl * NF + (((col >> 3) ^ (nl & 7)) << 3) + (col & 7);
                    float xv = bf2f(xs[addr]);
                    float nv = bf2f(ns[addr]);
                    float gp = ag[q], bp = ab[q];
                    float gamma = (gp >= 0.f ? gp : 0.2f * gp) + 1.0f;
                    float beta  = (bp >= 0.f ? bp : 0.2f * bp);
                    float o = xv + gamma * rc[j] + beta - nv;
                    if (ng < NN) outp[ng * NF + col] = o;
                    zs[addr] = f2bf(o + bf2f(zs[addr]));   // t = output + z, in place
                }
            }
        }
        __syncthreads();

        // ---- pass 2: h_k = (t @ lin^T + bias) * invd ----
        #pragma unroll 1
        for (int rg = 0; rg < 4; ++rg) {
            bf16x8 of[4];
            #pragma unroll
            for (int kb = 0; kb < 4; ++kb) {
                int row = rg * 16 + lr;
                int swz = (((kb * 4 + lg) ^ (row & 7)) << 3);
                of[kb] = *(const bf16x8*)(zs + row * NF + swz);
            }
            float invdq[4];
            #pragma unroll
            for (int q = 0; q < 4; ++q)
                invdq[q] = 1.0f / ((float)degr[min(node0 + rg * 16 + lg * 4 + q, NN - 1)] + 1.0f);
            #pragma unroll
            for (int j = 0; j < 2; ++j) {
                f32x4 as = {0.f, 0.f, 0.f, 0.f};
                #pragma unroll
                for (int kb = 0; kb < 4; ++kb)
                    as = __builtin_amdgcn_mfma_f32_16x16x32_bf16(of[kb], wf[j][4][kb], as, 0, 0, 0);
                int col = (2 * w + j) * 16 + lr;
                #pragma unroll
                for (int q = 0; q < 4; ++q) {
                    int ng = node0 + rg * 16 + lg * 4 + q;
                    if (ng < NN) hko[ng * NF + col] = (as[q] + bc[j]) * invdq[q];
                }
            }
        }
        __syncthreads();   // zs/xs/ns reused by next tile's stage
    }
}

// ---------------------------------------------------------------------------
extern "C" void kernel_launch(void* const* d_in, const int* in_sizes, int n_in,
                              void* d_out, int out_size, void* d_ws, size_t ws_size,
                              hipStream_t stream) {
    const float* x    = (const float*)d_in[0];
    const int*   ei   = (const int*)d_in[1];
    const float* g1   = (const float*)d_in[3];
    const float* g2   = (const float*)d_in[4];
    const float* b1   = (const float*)d_in[5];
    const float* b2   = (const float*)d_in[6];
    const float* rv   = (const float*)d_in[7];
    const float* lin  = (const float*)d_in[8];
    const float* bias = (const float*)d_in[9];

    float* dinv = (float*)d_ws;                  // N
    int* degr   = (int*)(dinv + NN);             // N
    int* offs_r = degr + NN;                     // N+1
    int* offs_c = offs_r + (NN + 1);             // N+1
    int* csr_r  = offs_c + (NN + 1);             // E
    int* csr_c  = csr_r + NE;                    // E
    unsigned* partR = (unsigned*)(csr_c + NE);   // E
    unsigned* partC = partR + NE;                // E
    int* gcnt   = (int*)(partC + NE);            // 2*NB (zeroed)
    int* gcur   = gcnt + 2 * NB;                 // 2*NB
    int* baseR  = gcur + 2 * NB;                 // NB+1
    int* baseC  = baseR + (NB + 1);              // NB+1
    uintptr_t p = (uintptr_t)(baseC + NB + 1);
    p = (p + 15) & ~(uintptr_t)15;
    short* xbf  = (short*)p;                     // N*F bf16
    short* nbbf = xbf + NN * NF;                 // N*F bf16
    short* zbf  = nbbf + NN * NF;                // N*F bf16
    short* wbf  = zbf + NN * NF;                 // 5*128*128 bf16

    float* hko  = (float*)d_out;                 // N*F (h_k)
    float* outp = hko + NN * NF;                 // N*F (output)

    hipMemsetAsync(gcnt, 0, 2 * NB * sizeof(int), stream);

    p0_count_kernel<<<PBLOCKS, 256, 0, stream>>>(ei, gcnt);
    p1_scan_kernel<<<1, 256, 0, stream>>>(gcnt, baseR, baseC, gcur);
    p2_partition_kernel<<<PBLOCKS, 256, 0, stream>>>(ei, gcur, partR, partC);
    p3_build_kernel<<<2 * NB, 256, 0, stream>>>(partR, partC, baseR, baseC,
                                                offs_r, offs_c, csr_r, csr_c, degr, dinv);
    convert_x_kernel<<<(NN * NF / 8 + 255) / 256, 256, 0, stream>>>(x, xbf);
    convert_w_kernel<<<(5 * NF * NF + 255) / 256, 256, 0, stream>>>(g1, g2, b1, b2, lin, wbf);
    gather_fused_kernel<<<(NN + 15) / 16, 256, 0, stream>>>(offs_r, csr_r, offs_c, csr_c,
                                                            xbf, dinv, nbbf, zbf);
    film_mfma_kernel<<<FBLOCKS, 256, 0, stream>>>(xbf, nbbf, zbf, wbf, rv, bias, degr,
                                                  outp, hko);
}